// Round 5
// baseline (5576.187 us; speedup 1.0000x reference)
//
#include <hip/hip_runtime.h>
#include <hip/hip_bf16.h>
#include <stdint.h>

typedef uint32_t u32;

#define DELTAF 1e-6f
#define CLIPF 20.0f

__device__ __forceinline__ float bl(u32 u) { return __uint_as_float(u << 16); }
__device__ __forceinline__ float bh(u32 u) { return __uint_as_float(u & 0xffff0000u); }
__device__ __forceinline__ float sigf(float x) { return 1.f / (1.f + expf(-x)); }
__device__ __forceinline__ float softplusf(float x) { return fmaxf(x, 0.f) + log1pf(expf(-fabsf(x))); }
__device__ __forceinline__ u32 f2b(float f) {
  u32 b = __float_as_uint(f);
  return (b + 0x7fffu + ((b >> 16) & 1u)) >> 16;
}
__device__ __forceinline__ u32 pk2(float a, float b) { return f2b(a) | (f2b(b) << 16); }

// dot over 4*n4 elements, f32 weights streamed from global
__device__ __forceinline__ float dotgf(const float* row, const float* x, int n4) {
  float a = 0.f;
  for (int i = 0; i < n4; ++i) {
    float4 w = ((const float4*)row)[i];
    float4 xv = ((const float4*)x)[i];
    a = fmaf(w.x, xv.x, a);
    a = fmaf(w.y, xv.y, a);
    a = fmaf(w.z, xv.z, a);
    a = fmaf(w.w, xv.w, a);
  }
  return a;
}

// ---------------- prep kernels (gi_emb precompute) ----------------
__global__ void prep_enc(const float* __restrict__ emb, const int* __restrict__ seq,
                         const float* __restrict__ Wih, const float* __restrict__ bih,
                         float* __restrict__ giE)
{
  __shared__ __align__(16) float sx[64];
  const int it = blockIdx.x, t = threadIdx.x;
  if (t < 64) sx[t] = emb[(size_t)seq[it]*64 + t];
  __syncthreads();
  if (t < 192) giE[it*192 + t] = bih[t] + dotgf(Wih + (size_t)t*128, sx, 16);
}

__global__ void prep_dec(const float* __restrict__ emb2, const int* __restrict__ seq3,
                         const float* __restrict__ Wih, const float* __restrict__ bih,
                         float* __restrict__ giE)
{
  __shared__ __align__(16) float sx[64];
  const int it = blockIdx.x, t = threadIdx.x;
  const int tok = (it == 0) ? 136 : seq3[it-1];
  if (t < 64) sx[t] = emb2[(size_t)tok*64 + t];
  __syncthreads();
  if (t < 384) giE[it*384 + t] = bih[t] + dotgf(Wih + (size_t)t*192, sx, 16);
}

// ---------------- weight transpose/pack into workspace ----------------
// region layout (4-byte elements, offsets within pk):
//      0 : pWB1 f32[12288]  Whh1^T  float2-interleaved [k2][r] (f32 flat (k2*192+r)*2+j)
//  12288 : pWB2 f32[12288]
//  24576 : pWC1 u32[8448]   iW1^T   bf16-pair [k2][r], k2<32, r<264
//  33024 : pWC2 u32[8448]
//  41472 : pWih u32[24576]  dec Wih^T (x-part cols 64..191) bf16-pair [k2][r], k2<64, r<384
//  66048 : pWhh u32[24576]  dec Whh^T bf16-pair [k2][r]
//  90624 : pIfw u32[8704]   ifw^T bf16-pair [k2][r], k2<64, r<136
__global__ void pack_weights(const float* __restrict__ e1_Whh, const float* __restrict__ e1_iW,
                             const float* __restrict__ e2_Whh, const float* __restrict__ e2_iW,
                             const float* __restrict__ dWih, const float* __restrict__ dWhh,
                             const float* __restrict__ ifwW, float* __restrict__ pk)
{
  const int i = blockIdx.x * 256 + threadIdx.x;
  u32* pku = (u32*)pk;
  if (i < 12288) {                       // pWB1
    int r = i >> 6, k = i & 63;
    pk[(k >> 1)*384 + 2*r + (k & 1)] = e1_Whh[r*64 + k];
  } else if (i < 24576) {                // pWB2
    int p = i - 12288;
    int r = p >> 6, k = p & 63;
    pk[12288 + (k >> 1)*384 + 2*r + (k & 1)] = e2_Whh[r*64 + k];
  } else if (i < 33024) {                // pWC1
    int p = i - 24576;
    int r = p >> 5, k2 = p & 31;
    pku[24576 + k2*264 + r] = pk2(e1_iW[r*64 + 2*k2], e1_iW[r*64 + 2*k2 + 1]);
  } else if (i < 41472) {                // pWC2
    int p = i - 33024;
    int r = p >> 5, k2 = p & 31;
    pku[33024 + k2*264 + r] = pk2(e2_iW[r*64 + 2*k2], e2_iW[r*64 + 2*k2 + 1]);
  } else if (i < 66048) {                // pWih (dec, x-part)
    int p = i - 41472;
    int r = p >> 6, k2 = p & 63;
    pku[41472 + k2*384 + r] = pk2(dWih[r*192 + 64 + 2*k2], dWih[r*192 + 64 + 2*k2 + 1]);
  } else if (i < 90624) {                // pWhh (dec)
    int p = i - 66048;
    int r = p >> 6, k2 = p & 63;
    pku[66048 + k2*384 + r] = pk2(dWhh[r*128 + 2*k2], dWhh[r*128 + 2*k2 + 1]);
  } else if (i < 99328) {                // pIfw
    int p = i - 90624;
    int r = p >> 6, k2 = p & 63;
    pku[90624 + k2*136 + r] = pk2(ifwW[r*128 + 2*k2], ifwW[r*128 + 2*k2 + 1]);
  }
}

// ---------------- encoder: 512 sequential DNC steps, 1 block per encoder ----------------
// stout layout per encoder (1440 f32):
//  [0,64) h | [64,128) lr | [128,144) rw | [144,160) mem row norms | [160,1184) mem | [1184,1440) link
__global__ __launch_bounds__(512) void enc_kernel(
    const float* __restrict__ Wih1, const float* __restrict__ bhh1, const float* __restrict__ ib1,
    const float* __restrict__ Wih2, const float* __restrict__ bhh2, const float* __restrict__ ib2,
    const float* __restrict__ giE_all, const float* __restrict__ pk, float* __restrict__ stout)
{
  __shared__ __align__(16) float s_WA[12288];   // gi weights: f32 float2-interleaved [k2][r]
  __shared__ __align__(16) float s_h[64];
  __shared__ __align__(16) float s_hc[64];
  __shared__ __align__(16) float s_lr[64];
  __shared__ float s_gi[192], s_gh[192], s_xi[264];
  __shared__ __align__(16) float s_mem[16][64];
  __shared__ float s_link[16][16];
  __shared__ float s_prec[2][16];
  __shared__ __align__(16) float s_rw[16];
  __shared__ __align__(16) float s_ww[16];
  __shared__ __align__(16) float s_usage[16];
  __shared__ float s_norm[16], s_sim[16], s_fw[16], s_bw[16];
  __shared__ float s_ev[64], s_wv[64];
  __shared__ float s_sc[8]; // 0:rs 1:ws 3:ag 4:wg 5..7:rm
  __shared__ float s_bhh[192], s_ib[264];
  __shared__ float s_wkn, s_rkn, s_S;

  const int t = threadIdx.x;
  const int e = blockIdx.x;
  const float* Wih = e ? Wih2 : Wih1;
  const float* bhh = e ? bhh2 : bhh1;
  const float* ib  = e ? ib2  : ib1;
  const float* giE = giE_all + (size_t)e * 512 * 192;
  const float* pWB = pk + (size_t)e * 12288;              // gh weights f32 [k2][r] float2-interleave
  const u32*   pWC = (const u32*)(pk + 24576) + (size_t)e * 8448;  // iW bf16-pair [k2][r]

  // prologue: WA into LDS (transposed), biases, state init
  for (int i = t; i < 12288; i += 512) {
    int r = i >> 6, k = i & 63;
    s_WA[(k >> 1)*384 + 2*r + (k & 1)] = Wih[r*128 + 64 + k];
  }
  if (t < 192) { s_bhh[t] = bhh[t]; s_gh[t] = bhh[t]; }   // h0=0 -> gh_0 = bhh
  if (t < 264) s_ib[t] = ib[t];
  if (t < 64) { s_h[t] = 0.f; s_lr[t] = 0.f; }
  if (t < 16) {
    s_rw[t] = DELTAF; s_ww[t] = DELTAF; s_usage[t] = 0.f; s_norm[t] = 0.f;
    s_prec[0][t] = 0.f; s_prec[1][t] = 0.f;
  }
  { float* mf = &s_mem[0][0]; for (int i = t; i < 1024; i += 512) mf[i] = 0.f; }
  if (t < 256) (&s_link[0][0])[t] = 0.f;
  __syncthreads();

  float gcur = (t < 192) ? giE[t] : 0.f;   // prefetched gi_emb for step 0
  int pb = 0;

  for (int it = 0; it < 512; ++it) {
    // ---- A: gi GEMV from LDS weights (gh already computed last step's phase C) ----
    if (t < 192) {
      int nx = (it + 1 < 512) ? (it + 1) : 511;
      float gn = giE[nx*192 + t];              // prefetch next step
      float a0 = 0.f, a1 = 0.f;
#pragma unroll
      for (int k2 = 0; k2 < 32; k2 += 2) {
        float2 w0 = ((const float2*)s_WA)[k2*192 + t];
        float2 w1 = ((const float2*)s_WA)[(k2+1)*192 + t];
        float4 xv = *(const float4*)&s_lr[2*k2];
        a0 = fmaf(w0.x, xv.x, a0); a0 = fmaf(w0.y, xv.y, a0);
        a1 = fmaf(w1.x, xv.z, a1); a1 = fmaf(w1.y, xv.w, a1);
      }
      s_gi[t] = gcur + a0 + a1;
      gcur = gn;
    }
    __syncthreads();
    // ---- B: GRU combine ----
    if (t < 64) {
      float r = sigf(s_gi[t] + s_gh[t]);
      float z = sigf(s_gi[64+t] + s_gh[64+t]);
      float n = tanhf(s_gi[128+t] + r*s_gh[128+t]);
      float h = (1.f - z)*n + z*s_h[t];
      s_h[t] = h;
      s_hc[t] = fminf(fmaxf(h, -CLIPF), CLIPF);
    }
    __syncthreads();
    // ---- C: xi GEMV (streamed bf16 iW)  ||  gh GEMV for NEXT step (streamed f32 Whh) ----
    if (t < 132) {
      float c0 = 0.f, c1 = 0.f;
#pragma unroll 8
      for (int k2 = 0; k2 < 32; ++k2) {
        uint2 u = *(const uint2*)&pWC[k2*264 + 2*t];
        float2 xv = *(const float2*)&s_hc[2*k2];
        c0 = fmaf(bl(u.x), xv.x, c0); c0 = fmaf(bh(u.x), xv.y, c0);
        c1 = fmaf(bl(u.y), xv.x, c1); c1 = fmaf(bh(u.y), xv.y, c1);
      }
      s_xi[2*t]   = s_ib[2*t]   + c0;
      s_xi[2*t+1] = s_ib[2*t+1] + c1;
    } else if (t >= 192 && t < 384) {
      int r = t - 192;
      float a0 = 0.f, a1 = 0.f;
#pragma unroll 8
      for (int k2 = 0; k2 < 32; ++k2) {
        float2 w = *(const float2*)&pWB[(k2*192 + r)*2];
        float2 xv = *(const float2*)&s_h[2*k2];
        a0 = fmaf(w.x, xv.x, a0); a1 = fmaf(w.y, xv.y, a1);
      }
      s_gh[r] = s_bhh[r] + a0 + a1;      // consumed by next step's phase B
    }
    __syncthreads();
    // ---- S1: write-key sim (raw) + activations + key norms + usage + scalars ----
    {
      int m = t >> 5, l = t & 31;
      float wkl = tanhf(s_xi[65+l]);
      float wkh = tanhf(s_xi[65+32+l]);
      float p = fmaf(wkl, s_mem[m][l], wkh * s_mem[m][l+32]);
      p += __shfl_xor(p,1); p += __shfl_xor(p,2); p += __shfl_xor(p,4);
      p += __shfl_xor(p,8); p += __shfl_xor(p,16);
      if (l == 0) s_sim[m] = p;   // raw dot; normalized in S2
    }
    if (t < 64) {
      s_ev[t] = sigf(s_xi[130+t]);
      s_wv[t] = tanhf(s_xi[194+t]);
    } else if (t < 128) {
      int l = t - 64;                       // read-key norm
      float v = tanhf(s_xi[l]);
      float p = v*v;
      p += __shfl_xor(p,1); p += __shfl_xor(p,2); p += __shfl_xor(p,4);
      p += __shfl_xor(p,8); p += __shfl_xor(p,16); p += __shfl_xor(p,32);
      if (l == 0) s_rkn = sqrtf(p);
    } else if (t < 192) {
      int l = t - 128;                      // write-key norm
      float v = tanhf(s_xi[65+l]);
      float p = v*v;
      p += __shfl_xor(p,1); p += __shfl_xor(p,2); p += __shfl_xor(p,4);
      p += __shfl_xor(p,8); p += __shfl_xor(p,16); p += __shfl_xor(p,32);
      if (l == 0) s_wkn = sqrtf(p);
    } else if (t < 208) {
      int j = t - 192;                      // usage update (prev ww, prev rw, this fg)
      float fg = sigf(s_xi[258]);
      float u = s_usage[j];
      u = u + (1.f - u) * s_ww[j];
      u = u * (1.f - fg * s_rw[j]);
      s_usage[j] = u;
    } else if (t == 208) s_sc[0] = softplusf(s_xi[64]);
    else if (t == 209) s_sc[1] = softplusf(s_xi[129]);
    else if (t == 210) s_sc[3] = sigf(s_xi[259]);
    else if (t == 211) s_sc[4] = sigf(s_xi[260]);
    else if (t == 212) {
      float a = s_xi[261], b = s_xi[262], c = s_xi[263];
      float mx = fmaxf(a, fmaxf(b, c));
      float ea = expf(a-mx), eb = expf(b-mx), ec = expf(c-mx);
      float s = ea + eb + ec;
      s_sc[5] = ea/s; s_sc[6] = eb/s; s_sc[7] = ec/s;
    }
    __syncthreads();
    // ---- S2: write softmax + allocation + write weights (wave 0, lanes 0..15) ----
    if (t < 16) {
      float x = s_sim[t] / ((s_norm[t] + DELTAF) * (s_wkn + DELTAF)) * s_sc[1];
      float mx = x;
      mx = fmaxf(mx, __shfl_xor(mx,1)); mx = fmaxf(mx, __shfl_xor(mx,2));
      mx = fmaxf(mx, __shfl_xor(mx,4)); mx = fmaxf(mx, __shfl_xor(mx,8));
      float ex = expf(x - mx);
      float sm = ex;
      sm += __shfl_xor(sm,1); sm += __shfl_xor(sm,2); sm += __shfl_xor(sm,4); sm += __shfl_xor(sm,8);
      float wcw = ex / sm;
      float4 u0 = ((const float4*)s_usage)[0];
      float4 u1 = ((const float4*)s_usage)[1];
      float4 u2 = ((const float4*)s_usage)[2];
      float4 u3 = ((const float4*)s_usage)[3];
      float uj[16] = {u0.x,u0.y,u0.z,u0.w, u1.x,u1.y,u1.z,u1.w,
                      u2.x,u2.y,u2.z,u2.w, u3.x,u3.y,u3.z,u3.w};
      float um = DELTAF + (1.f - DELTAF) * s_usage[t];
      float prod = 1.f;
#pragma unroll
      for (int j = 0; j < 16; ++j) {
        float v = DELTAF + (1.f - DELTAF) * uj[j];
        bool before = (v < um) || ((v == um) && (j < t));  // stable argsort order
        prod *= before ? v : 1.f;
      }
      float alloc = (1.f - um) * prod;
      float ww = s_sc[4] * (s_sc[3]*alloc + (1.f - s_sc[3])*wcw);
      float S = ww;
      S += __shfl_xor(S,1); S += __shfl_xor(S,2); S += __shfl_xor(S,4); S += __shfl_xor(S,8);
      s_ww[t] = ww;
      if (t == 0) s_S = S;
    }
    __syncthreads();
    // ---- S3: memory write + link update (+in-register fw) + precedence ----
    {
#pragma unroll
      for (int q = 0; q < 2; ++q) {
        int idx = t + q*512;
        int m = idx >> 6, wi = idx & 63;
        float wwm = s_ww[m];
        s_mem[m][wi] = s_mem[m][wi] * (1.f - wwm * s_ev[wi]) + wwm * s_wv[wi];
      }
    }
    if (t < 256) {
      int i = t >> 4, j = t & 15;
      float lv = (i == j) ? 0.f
               : ((1.f - s_ww[i] - s_ww[j]) * s_link[i][j] + s_ww[i] * s_prec[pb][j]);
      s_link[i][j] = lv;
      float p = lv * s_rw[j];
      p += __shfl_xor(p,1); p += __shfl_xor(p,2); p += __shfl_xor(p,4); p += __shfl_xor(p,8);
      if (j == 0) s_fw[i] = p;
    } else if (t < 272) {
      int j = t - 256;
      s_prec[pb^1][j] = (1.f - s_S) * s_prec[pb][j] + s_ww[j];
    }
    __syncthreads();
    // ---- S4: read-key sim (raw) + post-write norms (dual reduce) + bw ----
    {
      int m = t >> 5, l = t & 31;
      float rkl = tanhf(s_xi[l]);
      float rkh = tanhf(s_xi[l+32]);
      float ml = s_mem[m][l], mh = s_mem[m][l+32];
      float p = fmaf(rkl, ml, rkh * mh);
      float q = fmaf(ml, ml, mh * mh);
      p += __shfl_xor(p,1);  q += __shfl_xor(q,1);
      p += __shfl_xor(p,2);  q += __shfl_xor(q,2);
      p += __shfl_xor(p,4);  q += __shfl_xor(q,4);
      p += __shfl_xor(p,8);  q += __shfl_xor(q,8);
      p += __shfl_xor(p,16); q += __shfl_xor(q,16);
      if (l == 0) { s_sim[m] = p; s_norm[m] = sqrtf(q); }  // norm carried to next step
    }
    if (t >= 496) {
      int i = t - 496;
      float a = 0.f;
#pragma unroll
      for (int j = 0; j < 16; ++j) a = fmaf(s_link[j][i], s_rw[j], a);
      s_bw[i] = a;
    }
    __syncthreads();
    // ---- S5: read softmax + read weights + read vector (wave 0) ----
    if (t < 64) {
      float rwv = 0.f;
      if (t < 16) {
        float x = s_sim[t] / ((s_norm[t] + DELTAF) * (s_rkn + DELTAF)) * s_sc[0];
        float mx = x;
        mx = fmaxf(mx, __shfl_xor(mx,1)); mx = fmaxf(mx, __shfl_xor(mx,2));
        mx = fmaxf(mx, __shfl_xor(mx,4)); mx = fmaxf(mx, __shfl_xor(mx,8));
        float ex = expf(x - mx);
        float sm = ex;
        sm += __shfl_xor(sm,1); sm += __shfl_xor(sm,2); sm += __shfl_xor(sm,4); sm += __shfl_xor(sm,8);
        float cw = ex / sm;
        rwv = s_sc[5]*s_bw[t] + s_sc[6]*s_fw[t] + s_sc[7]*cw;
        s_rw[t] = rwv;
      }
      float a = 0.f;
#pragma unroll
      for (int m = 0; m < 16; ++m) a = fmaf(__shfl(rwv, m), s_mem[m][t], a);
      s_lr[t] = a;
    }
    pb ^= 1;
    __syncthreads();
  }

  float* so = stout + (size_t)e * 1440;
  if (t < 64) { so[t] = s_h[t]; so[64+t] = s_lr[t]; }
  if (t < 16) { so[128+t] = s_rw[t]; so[144+t] = s_norm[t]; }
  { const float* mf = &s_mem[0][0]; for (int i = t; i < 1024; i += 512) so[160+i] = mf[i]; }
  if (t < 256) so[1184+t] = (&s_link[0][0])[t];
}

// ---------------- decoder: 65 sequential steps, streamed weights ----------------
__global__ __launch_bounds__(512) void dec_kernel(
    const float* __restrict__ bhh, const float* __restrict__ ifwb,
    const float* __restrict__ giE, const float* __restrict__ st,
    const float* __restrict__ pk, float* __restrict__ r12h)
{
  __shared__ u32 s_pIfw[8704];                 // ifw^T bf16-pair [k2][r] (34 KB)
  __shared__ __align__(16) float s_h[128];
  __shared__ __align__(16) float s_r12[128];
  __shared__ float s_gi[384], s_gh[384], s_xi[136];
  __shared__ __align__(16) float s_mem[2][16][64];
  __shared__ float s_link[2][16][16];
  __shared__ float s_rw[2][16], s_norm[2][16];
  __shared__ float s_sim[2][16], s_fw[2][16], s_bw[2][16];
  __shared__ float s_rs[2], s_rkn[2];
  __shared__ float s_rm[2][3];
  __shared__ float s_bhh[384], s_ifwb[136];

  const int t = threadIdx.x;
  const u32* pWih = (const u32*)(pk + 41472);
  const u32* pWhh = (const u32*)(pk + 66048);
  const u32* pIfw = (const u32*)(pk + 90624);

  for (int i = t; i < 8704; i += 512) s_pIfw[i] = pIfw[i];
  if (t < 384) s_bhh[t]  = bhh[t];
  if (t < 136) s_ifwb[t] = ifwb[t];
  if (t < 64) {
    s_h[t]      = st[t];        s_h[64+t]   = st[1440+t];
    s_r12[t]    = st[64+t];     s_r12[64+t] = st[1440+64+t];
  }
  if (t < 16) {
    s_rw[0][t]   = st[128+t];   s_rw[1][t]   = st[1440+128+t];
    s_norm[0][t] = st[144+t];   s_norm[1][t] = st[1440+144+t];
  }
  for (int i = t; i < 1024; i += 512) {
    (&s_mem[0][0][0])[i] = st[160+i];
    (&s_mem[1][0][0])[i] = st[1440+160+i];
  }
  if (t < 256) {
    (&s_link[0][0][0])[t] = st[1184+t];
    (&s_link[1][0][0])[t] = st[1440+1184+t];
  }
  __syncthreads();

  float2 gcur = (t < 192) ? *(const float2*)&giE[2*t] : make_float2(0.f, 0.f);

  for (int it = 0; it < 65; ++it) {
    // ---- P1: gi (x=[r1;r2]) + gh, rows 2t,2t+1, weights streamed from L2 ----
    if (t < 192) {
      int nx = (it + 1 < 65) ? (it + 1) : 64;
      float2 gn = *(const float2*)&giE[nx*384 + 2*t];
      float gA = 0.f, gB = 0.f, hA = 0.f, hB = 0.f;
#pragma unroll 8
      for (int k2 = 0; k2 < 64; ++k2) {
        uint2 wg = *(const uint2*)&pWih[k2*384 + 2*t];
        uint2 wh = *(const uint2*)&pWhh[k2*384 + 2*t];
        float2 xr = *(const float2*)&s_r12[2*k2];
        float2 xh = *(const float2*)&s_h[2*k2];
        gA = fmaf(bl(wg.x), xr.x, fmaf(bh(wg.x), xr.y, gA));
        gB = fmaf(bl(wg.y), xr.x, fmaf(bh(wg.y), xr.y, gB));
        hA = fmaf(bl(wh.x), xh.x, fmaf(bh(wh.x), xh.y, hA));
        hB = fmaf(bl(wh.y), xh.x, fmaf(bh(wh.y), xh.y, hB));
      }
      s_gi[2*t]   = gcur.x + gA;
      s_gi[2*t+1] = gcur.y + gB;
      s_gh[2*t]   = s_bhh[2*t]   + hA;
      s_gh[2*t+1] = s_bhh[2*t+1] + hB;
      gcur = gn;
    }
    __syncthreads();
    // ---- P2: GRU (H=128) ----
    if (t < 128) {
      float r = sigf(s_gi[t] + s_gh[t]);
      float z = sigf(s_gi[128+t] + s_gh[128+t]);
      float n = tanhf(s_gi[256+t] + r*s_gh[256+t]);
      s_h[t] = (1.f - z)*n + z*s_h[t];
    }
    __syncthreads();
    // ---- P3: interface GEMV from LDS (rows 2rp, 2rp+1) ----
    if (t >= 256 && t < 324) {
      int rp = t - 256;
      float c0 = 0.f, c1 = 0.f;
#pragma unroll 8
      for (int k2 = 0; k2 < 64; ++k2) {
        uint2 u = *(const uint2*)&s_pIfw[k2*136 + 2*rp];
        float2 xv = *(const float2*)&s_h[2*k2];
        c0 = fmaf(bl(u.x), xv.x, fmaf(bh(u.x), xv.y, c0));
        c1 = fmaf(bl(u.y), xv.x, fmaf(bh(u.y), xv.y, c1));
      }
      s_xi[2*rp]   = s_ifwb[2*rp]   + c0;
      s_xi[2*rp+1] = s_ifwb[2*rp+1] + c1;
    }
    __syncthreads();
    // ---- S1: per-half sim (raw) + rk norm + fw/bw + scalars ----
    {
      int half = t >> 8, u = t & 255;
      int m = u >> 4, l = u & 15;
      float p = 0.f;
#pragma unroll
      for (int i = 0; i < 4; ++i) {
        float rk = tanhf(s_xi[half*64 + l*4 + i]);
        p = fmaf(rk, s_mem[half][m][l*4+i], p);
      }
      p += __shfl_xor(p,1); p += __shfl_xor(p,2); p += __shfl_xor(p,4); p += __shfl_xor(p,8);
      if (l == 0) s_sim[half][m] = p;   // raw
      if (u < 64) {
        float v = tanhf(s_xi[half*64 + u]);
        float q = v*v;
        q += __shfl_xor(q,1); q += __shfl_xor(q,2); q += __shfl_xor(q,4);
        q += __shfl_xor(q,8); q += __shfl_xor(q,16); q += __shfl_xor(q,32);
        if (u == 0) s_rkn[half] = sqrtf(q);
      } else if (u < 80) {
        int i = u - 64;
        float a = 0.f;
#pragma unroll
        for (int j = 0; j < 16; ++j) a = fmaf(s_link[half][i][j], s_rw[half][j], a);
        s_fw[half][i] = a;
      } else if (u < 96) {
        int i = u - 80;
        float a = 0.f;
#pragma unroll
        for (int j = 0; j < 16; ++j) a = fmaf(s_link[half][j][i], s_rw[half][j], a);
        s_bw[half][i] = a;
      } else if (u == 96) {
        s_rs[half] = softplusf(s_xi[128 + half]);
        float a = s_xi[130 + half*3], b = s_xi[131 + half*3], c = s_xi[132 + half*3];
        float mx = fmaxf(a, fmaxf(b, c));
        float ea = expf(a-mx), eb = expf(b-mx), ec = expf(c-mx);
        float s = ea+eb+ec;
        s_rm[half][0] = ea/s; s_rm[half][1] = eb/s; s_rm[half][2] = ec/s;
      }
    }
    __syncthreads();
    // ---- S2: per-half softmax + rw + read vector; h store for deferred logits ----
    if (t < 128) {
      int half = t >> 6, lane = t & 63;
      float rwv = 0.f;
      if (lane < 16) {
        float x = s_sim[half][lane] / ((s_norm[half][lane] + DELTAF)*(s_rkn[half] + DELTAF)) * s_rs[half];
        float mx = x;
        mx = fmaxf(mx, __shfl_xor(mx,1)); mx = fmaxf(mx, __shfl_xor(mx,2));
        mx = fmaxf(mx, __shfl_xor(mx,4)); mx = fmaxf(mx, __shfl_xor(mx,8));
        float ex = expf(x - mx);
        float sm = ex;
        sm += __shfl_xor(sm,1); sm += __shfl_xor(sm,2); sm += __shfl_xor(sm,4); sm += __shfl_xor(sm,8);
        float cw = ex / sm;
        rwv = s_rm[half][0]*s_bw[half][lane] + s_rm[half][1]*s_fw[half][lane] + s_rm[half][2]*cw;
        s_rw[half][lane] = rwv;
      }
      float a = 0.f;
#pragma unroll
      for (int m = 0; m < 16; ++m) a = fmaf(__shfl(rwv, m), s_mem[half][m][t & 63], a);
      s_r12[half*64 + (t&63)] = a;
      r12h[it*256 + half*64 + (t&63)] = a;
    } else if (t < 256) {
      r12h[it*256 + t] = s_h[t - 128];
    }
    __syncthreads();
  }
}

// ---------------- deferred logits ----------------
__global__ void logits_kernel(
    const float* __restrict__ r2oW, const float* __restrict__ r2ob,
    const float* __restrict__ outW, const float* __restrict__ outb,
    const float* __restrict__ r12h, float* __restrict__ out)
{
  __shared__ __align__(16) float s_in[128];
  __shared__ __align__(16) float s_oh[128];
  const int it = blockIdx.x, t = threadIdx.x;
  if (t < 128) s_in[t] = r12h[it*256 + t];
  __syncthreads();
  if (t < 128) {
    float o = r2ob[t] + dotgf(r2oW + (size_t)t*128, s_in, 32);
    s_oh[t] = o + r12h[it*256 + 128 + t];
  }
  __syncthreads();
  if (t < 138) {
    out[it*138 + t] = outb[t] + dotgf(outW + (size_t)t*128, s_oh, 32);
  }
}

extern "C" void kernel_launch(void* const* d_in, const int* in_sizes, int n_in,
                              void* d_out, int out_size, void* d_ws, size_t ws_size,
                              hipStream_t stream) {
  (void)in_sizes; (void)n_in; (void)out_size; (void)ws_size;
  const float* emb0   = (const float*)d_in[0];
  const float* emb1   = (const float*)d_in[1];
  const float* emb2   = (const float*)d_in[2];
  const float* e1_Wih = (const float*)d_in[3];
  const float* e1_Whh = (const float*)d_in[4];
  const float* e1_bih = (const float*)d_in[5];
  const float* e1_bhh = (const float*)d_in[6];
  const float* e1_iW  = (const float*)d_in[7];
  const float* e1_ib  = (const float*)d_in[8];
  const float* e2_Wih = (const float*)d_in[9];
  const float* e2_Whh = (const float*)d_in[10];
  const float* e2_bih = (const float*)d_in[11];
  const float* e2_bhh = (const float*)d_in[12];
  const float* e2_iW  = (const float*)d_in[13];
  const float* e2_ib  = (const float*)d_in[14];
  const float* dWih   = (const float*)d_in[15];
  const float* dWhh   = (const float*)d_in[16];
  const float* dbih   = (const float*)d_in[17];
  const float* dbhh   = (const float*)d_in[18];
  const float* ifwW   = (const float*)d_in[19];
  const float* ifwb   = (const float*)d_in[20];
  const float* r2oW   = (const float*)d_in[21];
  const float* r2ob   = (const float*)d_in[22];
  const float* outW   = (const float*)d_in[23];
  const float* outb   = (const float*)d_in[24];
  const int* seq1     = (const int*)d_in[25];
  const int* seq2     = (const int*)d_in[26];
  const int* seq3     = (const int*)d_in[27];

  float* ws   = (float*)d_ws;
  float* giE1 = ws;                    // 512*192 = 98304
  float* giE2 = giE1 + 98304;          // 98304 (contiguous with giE1)
  float* giEd = giE2 + 98304;          // 65*384 = 24960
  float* st   = giEd + 24960;          // 2*1440 = 2880
  float* r12h = st + 2880;             // 65*256 = 16640
  float* pkw  = r12h + 16640;          // 99328 packed-weight region

  prep_enc<<<512, 192, 0, stream>>>(emb0, seq1, e1_Wih, e1_bih, giE1);
  prep_enc<<<512, 192, 0, stream>>>(emb1, seq2, e2_Wih, e2_bih, giE2);
  prep_dec<<<65, 384, 0, stream>>>(emb2, seq3, dWih, dbih, giEd);
  pack_weights<<<(99328 + 255) / 256, 256, 0, stream>>>(e1_Whh, e1_iW, e2_Whh, e2_iW,
                                                        dWih, dWhh, ifwW, pkw);
  enc_kernel<<<2, 512, 0, stream>>>(e1_Wih, e1_bhh, e1_ib, e2_Wih, e2_bhh, e2_ib,
                                    giE1, pkw, st);
  dec_kernel<<<1, 512, 0, stream>>>(dbhh, ifwb, giEd, st, pkw, r12h);
  logits_kernel<<<65, 256, 0, stream>>>(r2oW, r2ob, outW, outb, r12h, (float*)d_out);
}

// Round 6
// 4852.931 us; speedup vs baseline: 1.1490x; 1.1490x over previous
//
#include <hip/hip_runtime.h>
#include <hip/hip_bf16.h>
#include <stdint.h>

typedef uint32_t u32;

#define DELTAF 1e-6f
#define CLIPF 20.0f

__device__ __forceinline__ float bl(u32 u) { return __uint_as_float(u << 16); }
__device__ __forceinline__ float bh(u32 u) { return __uint_as_float(u & 0xffff0000u); }
__device__ __forceinline__ float sigf(float x) { return 1.f / (1.f + expf(-x)); }
__device__ __forceinline__ float softplusf(float x) { return fmaxf(x, 0.f) + log1pf(expf(-fabsf(x))); }
__device__ __forceinline__ u32 f2b(float f) {
  u32 b = __float_as_uint(f);
  return (b + 0x7fffu + ((b >> 16) & 1u)) >> 16;
}
__device__ __forceinline__ u32 pk2(float a, float b) { return f2b(a) | (f2b(b) << 16); }

// load 64 consecutive f32 -> bf16 RNE, pack into 32 u32 (registers)
__device__ __forceinline__ void ldrow64pk(u32* w, const float* p) {
  const float4* q = (const float4*)p;
#pragma unroll
  for (int i = 0; i < 16; ++i) {
    float4 v = q[i];
    w[2*i]   = pk2(v.x, v.y);
    w[2*i+1] = pk2(v.z, v.w);
  }
}

// load 128 consecutive f32 -> bf16 RNE, pack pairs into 64 u32
__device__ __forceinline__ void ldrow128pk(u32* w, const float* p) {
  const float4* q = (const float4*)p;
#pragma unroll
  for (int i = 0; i < 32; ++i) {
    float4 v = q[i];
    w[2*i]   = pk2(v.x, v.y);
    w[2*i+1] = pk2(v.z, v.w);
  }
}

// 64-long dot, packed bf16 weights (32 u32), x from LDS
__device__ __forceinline__ float dotp64(const u32* w, const float* x) {
  float a0 = 0.f, a1 = 0.f;
#pragma unroll
  for (int i = 0; i < 8; ++i) {
    float4 v0 = ((const float4*)x)[2*i+0];
    float4 v1 = ((const float4*)x)[2*i+1];
    u32 p0 = w[4*i+0], q0 = w[4*i+1], p1 = w[4*i+2], q1 = w[4*i+3];
    a0 = fmaf(bl(p0), v0.x, a0); a0 = fmaf(bh(p0), v0.y, a0);
    a0 = fmaf(bl(q0), v0.z, a0); a0 = fmaf(bh(q0), v0.w, a0);
    a1 = fmaf(bl(p1), v1.x, a1); a1 = fmaf(bh(p1), v1.y, a1);
    a1 = fmaf(bl(q1), v1.z, a1); a1 = fmaf(bh(q1), v1.w, a1);
  }
  return a0 + a1;
}

// 64-long dot, packed bf16 weights (32 u32), x gathered from wave lanes via shfl
__device__ __forceinline__ float dotp64_shfl(const u32* w, float x) {
  float a0 = 0.f, a1 = 0.f;
#pragma unroll
  for (int i = 0; i < 32; ++i) {
    u32 p = w[i];
    a0 = fmaf(bl(p), __shfl(x, 2*i),   a0);
    a1 = fmaf(bh(p), __shfl(x, 2*i+1), a1);
  }
  return a0 + a1;
}

// 128-long dot, packed bf16 weights in regs, x from LDS
__device__ __forceinline__ float dotp128(const u32* w, const float* x) {
  float a0 = 0.f, a1 = 0.f, a2 = 0.f, a3 = 0.f;
#pragma unroll
  for (int i = 0; i < 8; ++i) {
    float4 v0 = ((const float4*)x)[4*i+0];
    float4 v1 = ((const float4*)x)[4*i+1];
    float4 v2 = ((const float4*)x)[4*i+2];
    float4 v3 = ((const float4*)x)[4*i+3];
    u32 p0 = w[8*i+0], q0 = w[8*i+1], p1 = w[8*i+2], q1 = w[8*i+3];
    u32 p2 = w[8*i+4], q2 = w[8*i+5], p3 = w[8*i+6], q3 = w[8*i+7];
    a0 = fmaf(bl(p0), v0.x, a0); a0 = fmaf(bh(p0), v0.y, a0);
    a0 = fmaf(bl(q0), v0.z, a0); a0 = fmaf(bh(q0), v0.w, a0);
    a1 = fmaf(bl(p1), v1.x, a1); a1 = fmaf(bh(p1), v1.y, a1);
    a1 = fmaf(bl(q1), v1.z, a1); a1 = fmaf(bh(q1), v1.w, a1);
    a2 = fmaf(bl(p2), v2.x, a2); a2 = fmaf(bh(p2), v2.y, a2);
    a2 = fmaf(bl(q2), v2.z, a2); a2 = fmaf(bh(q2), v2.w, a2);
    a3 = fmaf(bl(p3), v3.x, a3); a3 = fmaf(bh(p3), v3.y, a3);
    a3 = fmaf(bl(q3), v3.z, a3); a3 = fmaf(bh(q3), v3.w, a3);
  }
  return (a0 + a1) + (a2 + a3);
}

// 64-long dot, packed bf16 weights (32 u32), 2 accumulators (dec rows 128..135 halves)
__device__ __forceinline__ float dotp64h(const u32* w, const float* x) {
  float a0 = 0.f, a1 = 0.f;
#pragma unroll
  for (int i = 0; i < 8; ++i) {
    float4 v0 = ((const float4*)x)[2*i+0];
    float4 v1 = ((const float4*)x)[2*i+1];
    u32 p0 = w[4*i+0], q0 = w[4*i+1], p1 = w[4*i+2], q1 = w[4*i+3];
    a0 = fmaf(bl(p0), v0.x, a0); a0 = fmaf(bh(p0), v0.y, a0);
    a0 = fmaf(bl(q0), v0.z, a0); a0 = fmaf(bh(q0), v0.w, a0);
    a1 = fmaf(bl(p1), v1.x, a1); a1 = fmaf(bh(p1), v1.y, a1);
    a1 = fmaf(bl(q1), v1.z, a1); a1 = fmaf(bh(q1), v1.w, a1);
  }
  return a0 + a1;
}

// dot over 4*n4 elements, f32 weights streamed from global
__device__ __forceinline__ float dotgf(const float* row, const float* x, int n4) {
  float a = 0.f;
  for (int i = 0; i < n4; ++i) {
    float4 w = ((const float4*)row)[i];
    float4 xv = ((const float4*)x)[i];
    a = fmaf(w.x, xv.x, a);
    a = fmaf(w.y, xv.y, a);
    a = fmaf(w.z, xv.z, a);
    a = fmaf(w.w, xv.w, a);
  }
  return a;
}

// ---------------- prep kernels (gi_emb precompute) ----------------
__global__ void prep_enc(const float* __restrict__ emb, const int* __restrict__ seq,
                         const float* __restrict__ Wih, const float* __restrict__ bih,
                         float* __restrict__ giE)
{
  __shared__ __align__(16) float sx[64];
  const int it = blockIdx.x, t = threadIdx.x;
  if (t < 64) sx[t] = emb[(size_t)seq[it]*64 + t];
  __syncthreads();
  if (t < 192) giE[it*192 + t] = bih[t] + dotgf(Wih + (size_t)t*128, sx, 16);
}

__global__ void prep_dec(const float* __restrict__ emb2, const int* __restrict__ seq3,
                         const float* __restrict__ Wih, const float* __restrict__ bih,
                         float* __restrict__ giE)
{
  __shared__ __align__(16) float sx[64];
  const int it = blockIdx.x, t = threadIdx.x;
  const int tok = (it == 0) ? 136 : seq3[it-1];
  if (t < 64) sx[t] = emb2[(size_t)tok*64 + t];
  __syncthreads();
  if (t < 384) giE[it*384 + t] = bih[t] + dotgf(Wih + (size_t)t*192, sx, 16);
}

// ---------------- weight transpose/pack into workspace (dec only is used) ----------------
__global__ void pack_weights(const float* __restrict__ dWih, const float* __restrict__ dWhh,
                             const float* __restrict__ ifwW, float* __restrict__ pk)
{
  const int i = blockIdx.x * 256 + threadIdx.x;
  u32* pku = (u32*)pk;
  if (i < 24576) {                       // pWih (dec, x-part) at offset 41472
    int r = i >> 6, k2 = i & 63;
    pku[41472 + k2*384 + r] = pk2(dWih[r*192 + 64 + 2*k2], dWih[r*192 + 64 + 2*k2 + 1]);
  } else if (i < 49152) {                // pWhh (dec) at offset 66048
    int p = i - 24576;
    int r = p >> 6, k2 = p & 63;
    pku[66048 + k2*384 + r] = pk2(dWhh[r*128 + 2*k2], dWhh[r*128 + 2*k2 + 1]);
  } else if (i < 57856) {                // pIfw at offset 90624
    int p = i - 49152;
    int r = p >> 6, k2 = p & 63;
    pku[90624 + k2*136 + r] = pk2(ifwW[r*128 + 2*k2], ifwW[r*128 + 2*k2 + 1]);
  }
}

// ---------------- encoder: 512 sequential DNC steps, 1 block per encoder ----------------
// 7 phases/step, zero global memory in steady state, weights in bf16 registers.
// stout layout per encoder (1440 f32):
//  [0,64) h | [64,128) lr | [128,144) rw | [144,160) mem row norms | [160,1184) mem | [1184,1440) link
__global__ __launch_bounds__(512) void enc_kernel(
    const float* __restrict__ Wih1, const float* __restrict__ Whh1, const float* __restrict__ bhh1,
    const float* __restrict__ iW1, const float* __restrict__ ib1,
    const float* __restrict__ Wih2, const float* __restrict__ Whh2, const float* __restrict__ bhh2,
    const float* __restrict__ iW2, const float* __restrict__ ib2,
    const float* __restrict__ giE_all, float* __restrict__ stout)
{
  __shared__ __align__(16) float s_giE[64*192];   // 64-step chunk of gi_emb (49 KB)
  __shared__ __align__(16) float s_lr[64];
  __shared__ float s_gi[192];
  __shared__ float s_ghb[2][192];                 // double-buffered gh (next-step pipeline)
  __shared__ float s_xi[264];
  __shared__ __align__(16) float s_mem[16][64];
  __shared__ float s_link[16][16];
  __shared__ float s_prec[2][16];
  __shared__ __align__(16) float s_rw[16];
  __shared__ __align__(16) float s_ww[16];
  __shared__ __align__(16) float s_usage[16];
  __shared__ float s_norm[16], s_sim[16], s_fw[16], s_bw[16];
  __shared__ float s_sc[8]; // 0:rs 1:ws 3:ag 4:wg 5..7:rm
  __shared__ float s_wkn, s_rkn, s_S;

  const int t = threadIdx.x;
  const int e = blockIdx.x;
  const float* Wih = e ? Wih2 : Wih1;
  const float* Whh = e ? Whh2 : Whh1;
  const float* bhh = e ? bhh2 : bhh1;
  const float* iW  = e ? iW2  : iW1;
  const float* ib  = e ? ib2  : ib1;
  const float* giE = giE_all + (size_t)e * 512 * 192;

  // --- register-resident bf16 weights ---
  u32 wA[32];   // t<192: gi row t (Wih cols 64..127)
  u32 wC[32];   // t<256: xi row t | 256<=t<448: gh row t-256 | t>=448: xi row 256+min(l,7)
  float bC = 0.f;
  if (t < 192) ldrow64pk(wA, Wih + (size_t)t*128 + 64);
  if (t < 256) {
    ldrow64pk(wC, iW + (size_t)t*64);
    if (t < 264 - 8) bC = ib[t]; else bC = ib[t];   // ib[t]
  } else if (t < 448) {
    ldrow64pk(wC, Whh + (size_t)(t-256)*64);
    bC = bhh[t-256];
  } else {
    int row = 256 + ((t - 448) < 8 ? (t - 448) : 7);
    ldrow64pk(wC, iW + (size_t)row*64);
    bC = ib[row];
  }

  // --- state init ---
  if (t < 192) s_ghb[0][t] = bhh[t];     // h0 = 0 -> gh(0) = bhh
  if (t < 64) s_lr[t] = 0.f;
  if (t < 16) {
    s_rw[t] = DELTAF; s_ww[t] = DELTAF; s_usage[t] = 0.f; s_norm[t] = 0.f;
    s_prec[0][t] = 0.f; s_prec[1][t] = 0.f;
  }
  { float* mf = &s_mem[0][0]; for (int i = t; i < 1024; i += 512) mf[i] = 0.f; }
  if (t < 256) (&s_link[0][0])[t] = 0.f;
  float h_reg = 0.f;                      // lane-owned h[t&63], carried across steps
  __syncthreads();

  int pb = 0;
  for (int it = 0; it < 512; ++it) {
    // ---- chunk refill (8x total): only place global memory is touched ----
    if ((it & 63) == 0) {
      const float4* src = (const float4*)(giE + it*192);
      float4* dst = (float4*)s_giE;
      for (int i = t; i < 64*192/4; i += 512) dst[i] = src[i];
      __syncthreads();
    }
    // ---- A: gi GEMV (reg weights, x = lr from LDS) ----
    if (t < 192) s_gi[t] = s_giE[(it & 63)*192 + t] + dotp64(wA, s_lr);
    __syncthreads();
    // ---- C': redundant per-wave GRU + xi GEMV + next-step gh GEMV (shfl-gather) ----
    {
      int l = t & 63;
      const float* ghb = s_ghb[it & 1];
      float r = sigf(s_gi[l]       + ghb[l]);
      float z = sigf(s_gi[64 + l]  + ghb[64 + l]);
      float n = tanhf(s_gi[128 + l] + r * ghb[128 + l]);
      h_reg = (1.f - z) * n + z * h_reg;
      float hc = fminf(fmaxf(h_reg, -CLIPF), CLIPF);
      int wv = t >> 6;
      if (wv < 4) {                         // xi rows 0..255
        s_xi[t] = bC + dotp64_shfl(wC, hc);
      } else if (wv < 7) {                  // gh rows 0..191 for step it+1
        s_ghb[(it + 1) & 1][t - 256] = bC + dotp64_shfl(wC, h_reg);
      } else {                              // xi rows 256..263 (all lanes execute shfl)
        float a = dotp64_shfl(wC, hc);
        if (l < 8) s_xi[256 + l] = bC + a;
      }
    }
    __syncthreads();
    // ---- S1: write-key sim (raw) + key norms + usage + scalars ----
    {
      int m = t >> 5, l = t & 31;
      float wkl = tanhf(s_xi[65+l]);
      float wkh = tanhf(s_xi[65+32+l]);
      float p = fmaf(wkl, s_mem[m][l], wkh * s_mem[m][l+32]);
      p += __shfl_xor(p,1); p += __shfl_xor(p,2); p += __shfl_xor(p,4);
      p += __shfl_xor(p,8); p += __shfl_xor(p,16);
      if (l == 0) s_sim[m] = p;   // raw dot; normalized in S2
    }
    if (t >= 64 && t < 128) {
      int l = t - 64;                       // read-key norm
      float v = tanhf(s_xi[l]);
      float p = v*v;
      p += __shfl_xor(p,1); p += __shfl_xor(p,2); p += __shfl_xor(p,4);
      p += __shfl_xor(p,8); p += __shfl_xor(p,16); p += __shfl_xor(p,32);
      if (l == 0) s_rkn = sqrtf(p);
    } else if (t >= 128 && t < 192) {
      int l = t - 128;                      // write-key norm
      float v = tanhf(s_xi[65+l]);
      float p = v*v;
      p += __shfl_xor(p,1); p += __shfl_xor(p,2); p += __shfl_xor(p,4);
      p += __shfl_xor(p,8); p += __shfl_xor(p,16); p += __shfl_xor(p,32);
      if (l == 0) s_wkn = sqrtf(p);
    } else if (t >= 192 && t < 208) {
      int j = t - 192;                      // usage update (prev ww, prev rw, this fg)
      float fg = sigf(s_xi[258]);
      float u = s_usage[j];
      u = u + (1.f - u) * s_ww[j];
      u = u * (1.f - fg * s_rw[j]);
      s_usage[j] = u;
    } else if (t == 208) s_sc[0] = softplusf(s_xi[64]);
    else if (t == 209) s_sc[1] = softplusf(s_xi[129]);
    else if (t == 210) s_sc[3] = sigf(s_xi[259]);
    else if (t == 211) s_sc[4] = sigf(s_xi[260]);
    else if (t == 212) {
      float a = s_xi[261], b = s_xi[262], c = s_xi[263];
      float mx = fmaxf(a, fmaxf(b, c));
      float ea = expf(a-mx), eb = expf(b-mx), ec = expf(c-mx);
      float s = ea + eb + ec;
      s_sc[5] = ea/s; s_sc[6] = eb/s; s_sc[7] = ec/s;
    }
    __syncthreads();
    // ---- S2: write softmax + allocation + write weights (wave 0, lanes 0..15) ----
    if (t < 16) {
      float x = s_sim[t] / ((s_norm[t] + DELTAF) * (s_wkn + DELTAF)) * s_sc[1];
      float mx = x;
      mx = fmaxf(mx, __shfl_xor(mx,1)); mx = fmaxf(mx, __shfl_xor(mx,2));
      mx = fmaxf(mx, __shfl_xor(mx,4)); mx = fmaxf(mx, __shfl_xor(mx,8));
      float ex = expf(x - mx);
      float sm = ex;
      sm += __shfl_xor(sm,1); sm += __shfl_xor(sm,2); sm += __shfl_xor(sm,4); sm += __shfl_xor(sm,8);
      float wcw = ex / sm;
      float4 u0 = ((const float4*)s_usage)[0];
      float4 u1 = ((const float4*)s_usage)[1];
      float4 u2 = ((const float4*)s_usage)[2];
      float4 u3 = ((const float4*)s_usage)[3];
      float uj[16] = {u0.x,u0.y,u0.z,u0.w, u1.x,u1.y,u1.z,u1.w,
                      u2.x,u2.y,u2.z,u2.w, u3.x,u3.y,u3.z,u3.w};
      float um = DELTAF + (1.f - DELTAF) * s_usage[t];
      float prod = 1.f;
#pragma unroll
      for (int j = 0; j < 16; ++j) {
        float v = DELTAF + (1.f - DELTAF) * uj[j];
        bool before = (v < um) || ((v == um) && (j < t));  // stable argsort order
        prod *= before ? v : 1.f;
      }
      float alloc = (1.f - um) * prod;
      float ww = s_sc[4] * (s_sc[3]*alloc + (1.f - s_sc[3])*wcw);
      float S = ww;
      S += __shfl_xor(S,1); S += __shfl_xor(S,2); S += __shfl_xor(S,4); S += __shfl_xor(S,8);
      s_ww[t] = ww;
      if (t == 0) s_S = S;
    }
    __syncthreads();
    // ---- S3: memory write (ev/wv inline) + link update (+fw) + precedence ----
    {
#pragma unroll
      for (int q = 0; q < 2; ++q) {
        int idx = t + q*512;
        int m = idx >> 6, wi = idx & 63;
        float wwm = s_ww[m];
        float ev = sigf(s_xi[130+wi]);
        float wv = tanhf(s_xi[194+wi]);
        s_mem[m][wi] = s_mem[m][wi] * (1.f - wwm * ev) + wwm * wv;
      }
    }
    if (t < 256) {
      int i = t >> 4, j = t & 15;
      float lv = (i == j) ? 0.f
               : ((1.f - s_ww[i] - s_ww[j]) * s_link[i][j] + s_ww[i] * s_prec[pb][j]);
      s_link[i][j] = lv;
      float p = lv * s_rw[j];
      p += __shfl_xor(p,1); p += __shfl_xor(p,2); p += __shfl_xor(p,4); p += __shfl_xor(p,8);
      if (j == 0) s_fw[i] = p;
    } else if (t < 272) {
      int j = t - 256;
      s_prec[pb^1][j] = (1.f - s_S) * s_prec[pb][j] + s_ww[j];
    }
    __syncthreads();
    // ---- S4: read-key sim (raw) + post-write norms (dual reduce) + bw ----
    {
      int m = t >> 5, l = t & 31;
      float rkl = tanhf(s_xi[l]);
      float rkh = tanhf(s_xi[l+32]);
      float ml = s_mem[m][l], mh = s_mem[m][l+32];
      float p = fmaf(rkl, ml, rkh * mh);
      float q = fmaf(ml, ml, mh * mh);
      p += __shfl_xor(p,1);  q += __shfl_xor(q,1);
      p += __shfl_xor(p,2);  q += __shfl_xor(q,2);
      p += __shfl_xor(p,4);  q += __shfl_xor(q,4);
      p += __shfl_xor(p,8);  q += __shfl_xor(q,8);
      p += __shfl_xor(p,16); q += __shfl_xor(q,16);
      if (l == 0) { s_sim[m] = p; s_norm[m] = sqrtf(q); }  // norm carried to next step
    }
    if (t >= 496) {
      int i = t - 496;
      float a = 0.f;
#pragma unroll
      for (int j = 0; j < 16; ++j) a = fmaf(s_link[j][i], s_rw[j], a);
      s_bw[i] = a;
    }
    __syncthreads();
    // ---- S5: read softmax + read weights + read vector (wave 0) ----
    if (t < 64) {
      float rwv = 0.f;
      if (t < 16) {
        float x = s_sim[t] / ((s_norm[t] + DELTAF) * (s_rkn + DELTAF)) * s_sc[0];
        float mx = x;
        mx = fmaxf(mx, __shfl_xor(mx,1)); mx = fmaxf(mx, __shfl_xor(mx,2));
        mx = fmaxf(mx, __shfl_xor(mx,4)); mx = fmaxf(mx, __shfl_xor(mx,8));
        float ex = expf(x - mx);
        float sm = ex;
        sm += __shfl_xor(sm,1); sm += __shfl_xor(sm,2); sm += __shfl_xor(sm,4); sm += __shfl_xor(sm,8);
        float cw = ex / sm;
        rwv = s_sc[5]*s_bw[t] + s_sc[6]*s_fw[t] + s_sc[7]*cw;
        s_rw[t] = rwv;
      }
      float a = 0.f;
#pragma unroll
      for (int m = 0; m < 16; ++m) a = fmaf(__shfl(rwv, m), s_mem[m][t], a);
      s_lr[t] = a;
    }
    pb ^= 1;
    __syncthreads();
  }

  float* so = stout + (size_t)e * 1440;
  if (t < 64) { so[t] = h_reg; so[64+t] = s_lr[t]; }   // thread t owns h[t]
  if (t < 16) { so[128+t] = s_rw[t]; so[144+t] = s_norm[t]; }
  { const float* mf = &s_mem[0][0]; for (int i = t; i < 1024; i += 512) so[160+i] = mf[i]; }
  if (t < 256) so[1184+t] = (&s_link[0][0])[t];
}

// ---------------- decoder: 65 sequential steps, streamed weights (unchanged from R5) ----------------
__global__ __launch_bounds__(512) void dec_kernel(
    const float* __restrict__ bhh, const float* __restrict__ ifwb,
    const float* __restrict__ giE, const float* __restrict__ st,
    const float* __restrict__ pk, float* __restrict__ r12h)
{
  __shared__ u32 s_pIfw[8704];                 // ifw^T bf16-pair [k2][r] (34 KB)
  __shared__ __align__(16) float s_h[128];
  __shared__ __align__(16) float s_r12[128];
  __shared__ float s_gi[384], s_gh[384], s_xi[136];
  __shared__ __align__(16) float s_mem[2][16][64];
  __shared__ float s_link[2][16][16];
  __shared__ float s_rw[2][16], s_norm[2][16];
  __shared__ float s_sim[2][16], s_fw[2][16], s_bw[2][16];
  __shared__ float s_rs[2], s_rkn[2];
  __shared__ float s_rm[2][3];
  __shared__ float s_bhh[384], s_ifwb[136];

  const int t = threadIdx.x;
  const u32* pWih = (const u32*)(pk + 41472);
  const u32* pWhh = (const u32*)(pk + 66048);
  const u32* pIfw = (const u32*)(pk + 90624);

  for (int i = t; i < 8704; i += 512) s_pIfw[i] = pIfw[i];
  if (t < 384) s_bhh[t]  = bhh[t];
  if (t < 136) s_ifwb[t] = ifwb[t];
  if (t < 64) {
    s_h[t]      = st[t];        s_h[64+t]   = st[1440+t];
    s_r12[t]    = st[64+t];     s_r12[64+t] = st[1440+64+t];
  }
  if (t < 16) {
    s_rw[0][t]   = st[128+t];   s_rw[1][t]   = st[1440+128+t];
    s_norm[0][t] = st[144+t];   s_norm[1][t] = st[1440+144+t];
  }
  for (int i = t; i < 1024; i += 512) {
    (&s_mem[0][0][0])[i] = st[160+i];
    (&s_mem[1][0][0])[i] = st[1440+160+i];
  }
  if (t < 256) {
    (&s_link[0][0][0])[t] = st[1184+t];
    (&s_link[1][0][0])[t] = st[1440+1184+t];
  }
  __syncthreads();

  float2 gcur = (t < 192) ? *(const float2*)&giE[2*t] : make_float2(0.f, 0.f);

  for (int it = 0; it < 65; ++it) {
    // ---- P1: gi (x=[r1;r2]) + gh, rows 2t,2t+1, weights streamed from L2 ----
    if (t < 192) {
      int nx = (it + 1 < 65) ? (it + 1) : 64;
      float2 gn = *(const float2*)&giE[nx*384 + 2*t];
      float gA = 0.f, gB = 0.f, hA = 0.f, hB = 0.f;
#pragma unroll 8
      for (int k2 = 0; k2 < 64; ++k2) {
        uint2 wg = *(const uint2*)&pWih[k2*384 + 2*t];
        uint2 wh = *(const uint2*)&pWhh[k2*384 + 2*t];
        float2 xr = *(const float2*)&s_r12[2*k2];
        float2 xh = *(const float2*)&s_h[2*k2];
        gA = fmaf(bl(wg.x), xr.x, fmaf(bh(wg.x), xr.y, gA));
        gB = fmaf(bl(wg.y), xr.x, fmaf(bh(wg.y), xr.y, gB));
        hA = fmaf(bl(wh.x), xh.x, fmaf(bh(wh.x), xh.y, hA));
        hB = fmaf(bl(wh.y), xh.x, fmaf(bh(wh.y), xh.y, hB));
      }
      s_gi[2*t]   = gcur.x + gA;
      s_gi[2*t+1] = gcur.y + gB;
      s_gh[2*t]   = s_bhh[2*t]   + hA;
      s_gh[2*t+1] = s_bhh[2*t+1] + hB;
      gcur = gn;
    }
    __syncthreads();
    // ---- P2: GRU (H=128) ----
    if (t < 128) {
      float r = sigf(s_gi[t] + s_gh[t]);
      float z = sigf(s_gi[128+t] + s_gh[128+t]);
      float n = tanhf(s_gi[256+t] + r*s_gh[256+t]);
      s_h[t] = (1.f - z)*n + z*s_h[t];
    }
    __syncthreads();
    // ---- P3: interface GEMV from LDS (rows 2rp, 2rp+1) ----
    if (t >= 256 && t < 324) {
      int rp = t - 256;
      float c0 = 0.f, c1 = 0.f;
#pragma unroll 8
      for (int k2 = 0; k2 < 64; ++k2) {
        uint2 u = *(const uint2*)&s_pIfw[k2*136 + 2*rp];
        float2 xv = *(const float2*)&s_h[2*k2];
        c0 = fmaf(bl(u.x), xv.x, fmaf(bh(u.x), xv.y, c0));
        c1 = fmaf(bl(u.y), xv.x, fmaf(bh(u.y), xv.y, c1));
      }
      s_xi[2*rp]   = s_ifwb[2*rp]   + c0;
      s_xi[2*rp+1] = s_ifwb[2*rp+1] + c1;
    }
    __syncthreads();
    // ---- S1: per-half sim (raw) + rk norm + fw/bw + scalars ----
    {
      int half = t >> 8, u = t & 255;
      int m = u >> 4, l = u & 15;
      float p = 0.f;
#pragma unroll
      for (int i = 0; i < 4; ++i) {
        float rk = tanhf(s_xi[half*64 + l*4 + i]);
        p = fmaf(rk, s_mem[half][m][l*4+i], p);
      }
      p += __shfl_xor(p,1); p += __shfl_xor(p,2); p += __shfl_xor(p,4); p += __shfl_xor(p,8);
      if (l == 0) s_sim[half][m] = p;   // raw
      if (u < 64) {
        float v = tanhf(s_xi[half*64 + u]);
        float q = v*v;
        q += __shfl_xor(q,1); q += __shfl_xor(q,2); q += __shfl_xor(q,4);
        q += __shfl_xor(q,8); q += __shfl_xor(q,16); q += __shfl_xor(q,32);
        if (u == 0) s_rkn[half] = sqrtf(q);
      } else if (u < 80) {
        int i = u - 64;
        float a = 0.f;
#pragma unroll
        for (int j = 0; j < 16; ++j) a = fmaf(s_link[half][i][j], s_rw[half][j], a);
        s_fw[half][i] = a;
      } else if (u < 96) {
        int i = u - 80;
        float a = 0.f;
#pragma unroll
        for (int j = 0; j < 16; ++j) a = fmaf(s_link[half][j][i], s_rw[half][j], a);
        s_bw[half][i] = a;
      } else if (u == 96) {
        s_rs[half] = softplusf(s_xi[128 + half]);
        float a = s_xi[130 + half*3], b = s_xi[131 + half*3], c = s_xi[132 + half*3];
        float mx = fmaxf(a, fmaxf(b, c));
        float ea = expf(a-mx), eb = expf(b-mx), ec = expf(c-mx);
        float s = ea+eb+ec;
        s_rm[half][0] = ea/s; s_rm[half][1] = eb/s; s_rm[half][2] = ec/s;
      }
    }
    __syncthreads();
    // ---- S2: per-half softmax + rw + read vector; h store for deferred logits ----
    if (t < 128) {
      int half = t >> 6, lane = t & 63;
      float rwv = 0.f;
      if (lane < 16) {
        float x = s_sim[half][lane] / ((s_norm[half][lane] + DELTAF)*(s_rkn[half] + DELTAF)) * s_rs[half];
        float mx = x;
        mx = fmaxf(mx, __shfl_xor(mx,1)); mx = fmaxf(mx, __shfl_xor(mx,2));
        mx = fmaxf(mx, __shfl_xor(mx,4)); mx = fmaxf(mx, __shfl_xor(mx,8));
        float ex = expf(x - mx);
        float sm = ex;
        sm += __shfl_xor(sm,1); sm += __shfl_xor(sm,2); sm += __shfl_xor(sm,4); sm += __shfl_xor(sm,8);
        float cw = ex / sm;
        rwv = s_rm[half][0]*s_bw[half][lane] + s_rm[half][1]*s_fw[half][lane] + s_rm[half][2]*cw;
        s_rw[half][lane] = rwv;
      }
      float a = 0.f;
#pragma unroll
      for (int m = 0; m < 16; ++m) a = fmaf(__shfl(rwv, m), s_mem[half][m][t & 63], a);
      s_r12[half*64 + (t&63)] = a;
      r12h[it*256 + half*64 + (t&63)] = a;
    } else if (t < 256) {
      r12h[it*256 + t] = s_h[t - 128];
    }
    __syncthreads();
  }
}

// ---------------- deferred logits ----------------
__global__ void logits_kernel(
    const float* __restrict__ r2oW, const float* __restrict__ r2ob,
    const float* __restrict__ outW, const float* __restrict__ outb,
    const float* __restrict__ r12h, float* __restrict__ out)
{
  __shared__ __align__(16) float s_in[128];
  __shared__ __align__(16) float s_oh[128];
  const int it = blockIdx.x, t = threadIdx.x;
  if (t < 128) s_in[t] = r12h[it*256 + t];
  __syncthreads();
  if (t < 128) {
    float o = r2ob[t] + dotgf(r2oW + (size_t)t*128, s_in, 32);
    s_oh[t] = o + r12h[it*256 + 128 + t];
  }
  __syncthreads();
  if (t < 138) {
    out[it*138 + t] = outb[t] + dotgf(outW + (size_t)t*128, s_oh, 32);
  }
}

extern "C" void kernel_launch(void* const* d_in, const int* in_sizes, int n_in,
                              void* d_out, int out_size, void* d_ws, size_t ws_size,
                              hipStream_t stream) {
  (void)in_sizes; (void)n_in; (void)out_size; (void)ws_size;
  const float* emb0   = (const float*)d_in[0];
  const float* emb1   = (const float*)d_in[1];
  const float* emb2   = (const float*)d_in[2];
  const float* e1_Wih = (const float*)d_in[3];
  const float* e1_Whh = (const float*)d_in[4];
  const float* e1_bih = (const float*)d_in[5];
  const float* e1_bhh = (const float*)d_in[6];
  const float* e1_iW  = (const float*)d_in[7];
  const float* e1_ib  = (const float*)d_in[8];
  const float* e2_Wih = (const float*)d_in[9];
  const float* e2_Whh = (const float*)d_in[10];
  const float* e2_bih = (const float*)d_in[11];
  const float* e2_bhh = (const float*)d_in[12];
  const float* e2_iW  = (const float*)d_in[13];
  const float* e2_ib  = (const float*)d_in[14];
  const float* dWih   = (const float*)d_in[15];
  const float* dWhh   = (const float*)d_in[16];
  const float* dbih   = (const float*)d_in[17];
  const float* dbhh   = (const float*)d_in[18];
  const float* ifwW   = (const float*)d_in[19];
  const float* ifwb   = (const float*)d_in[20];
  const float* r2oW   = (const float*)d_in[21];
  const float* r2ob   = (const float*)d_in[22];
  const float* outW   = (const float*)d_in[23];
  const float* outb   = (const float*)d_in[24];
  const int* seq1     = (const int*)d_in[25];
  const int* seq2     = (const int*)d_in[26];
  const int* seq3     = (const int*)d_in[27];

  float* ws   = (float*)d_ws;
  float* giE1 = ws;                    // 512*192 = 98304
  float* giE2 = giE1 + 98304;          // 98304 (contiguous with giE1)
  float* giEd = giE2 + 98304;          // 65*384 = 24960
  float* st   = giEd + 24960;          // 2*1440 = 2880
  float* r12h = st + 2880;             // 65*256 = 16640
  float* pkw  = r12h + 16640;          // 99328 packed-weight region (dec uses 41472..99328)

  prep_enc<<<512, 192, 0, stream>>>(emb0, seq1, e1_Wih, e1_bih, giE1);
  prep_enc<<<512, 192, 0, stream>>>(emb1, seq2, e2_Wih, e2_bih, giE2);
  prep_dec<<<65, 384, 0, stream>>>(emb2, seq3, dWih, dbih, giEd);
  pack_weights<<<(57856 + 255) / 256, 256, 0, stream>>>(dWih, dWhh, ifwW, pkw);
  enc_kernel<<<2, 512, 0, stream>>>(e1_Wih, e1_Whh, e1_bhh, e1_iW, e1_ib,
                                    e2_Wih, e2_Whh, e2_bhh, e2_iW, e2_ib, giE1, st);
  dec_kernel<<<1, 512, 0, stream>>>(dbhh, ifwb, giEd, st, pkw, r12h);
  logits_kernel<<<65, 256, 0, stream>>>(r2oW, r2ob, outW, outb, r12h, (float*)d_out);
}

// Round 7
// 3755.257 us; speedup vs baseline: 1.4849x; 1.2923x over previous
//
#include <hip/hip_runtime.h>
#include <hip/hip_bf16.h>
#include <stdint.h>

typedef uint32_t u32;

#define DELTAF 1e-6f
#define CLIPF 20.0f

__device__ __forceinline__ float bl(u32 u) { return __uint_as_float(u << 16); }
__device__ __forceinline__ float bh(u32 u) { return __uint_as_float(u & 0xffff0000u); }
__device__ __forceinline__ float sigf(float x) { return 1.f / (1.f + expf(-x)); }
__device__ __forceinline__ float softplusf(float x) { return fmaxf(x, 0.f) + log1pf(expf(-fabsf(x))); }
__device__ __forceinline__ u32 f2b(float f) {
  u32 b = __float_as_uint(f);
  return (b + 0x7fffu + ((b >> 16) & 1u)) >> 16;
}
__device__ __forceinline__ u32 pk2(float a, float b) { return f2b(a) | (f2b(b) << 16); }

// load 64 consecutive f32 -> bf16 RNE, pack into 32 u32 (registers)
__device__ __forceinline__ void ldrow64pk(u32* w, const float* p) {
  const float4* q = (const float4*)p;
#pragma unroll
  for (int i = 0; i < 16; ++i) {
    float4 v = q[i];
    w[2*i]   = pk2(v.x, v.y);
    w[2*i+1] = pk2(v.z, v.w);
  }
}

// load 128 consecutive f32 -> bf16 RNE, pack pairs into 64 u32
__device__ __forceinline__ void ldrow128pk(u32* w, const float* p) {
  const float4* q = (const float4*)p;
#pragma unroll
  for (int i = 0; i < 32; ++i) {
    float4 v = q[i];
    w[2*i]   = pk2(v.x, v.y);
    w[2*i+1] = pk2(v.z, v.w);
  }
}

// 64-long dot, packed bf16 weights (32 u32), x from LDS (broadcast reads)
__device__ __forceinline__ float dotp64(const u32* w, const float* x) {
  float a0 = 0.f, a1 = 0.f;
#pragma unroll
  for (int i = 0; i < 8; ++i) {
    float4 v0 = ((const float4*)x)[2*i+0];
    float4 v1 = ((const float4*)x)[2*i+1];
    u32 p0 = w[4*i+0], q0 = w[4*i+1], p1 = w[4*i+2], q1 = w[4*i+3];
    a0 = fmaf(bl(p0), v0.x, a0); a0 = fmaf(bh(p0), v0.y, a0);
    a0 = fmaf(bl(q0), v0.z, a0); a0 = fmaf(bh(q0), v0.w, a0);
    a1 = fmaf(bl(p1), v1.x, a1); a1 = fmaf(bh(p1), v1.y, a1);
    a1 = fmaf(bl(q1), v1.z, a1); a1 = fmaf(bh(q1), v1.w, a1);
  }
  return a0 + a1;
}

// 128-long dot, packed bf16 weights in regs, x from LDS
__device__ __forceinline__ float dotp128(const u32* w, const float* x) {
  float a0 = 0.f, a1 = 0.f, a2 = 0.f, a3 = 0.f;
#pragma unroll
  for (int i = 0; i < 8; ++i) {
    float4 v0 = ((const float4*)x)[4*i+0];
    float4 v1 = ((const float4*)x)[4*i+1];
    float4 v2 = ((const float4*)x)[4*i+2];
    float4 v3 = ((const float4*)x)[4*i+3];
    u32 p0 = w[8*i+0], q0 = w[8*i+1], p1 = w[8*i+2], q1 = w[8*i+3];
    u32 p2 = w[8*i+4], q2 = w[8*i+5], p3 = w[8*i+6], q3 = w[8*i+7];
    a0 = fmaf(bl(p0), v0.x, a0); a0 = fmaf(bh(p0), v0.y, a0);
    a0 = fmaf(bl(q0), v0.z, a0); a0 = fmaf(bh(q0), v0.w, a0);
    a1 = fmaf(bl(p1), v1.x, a1); a1 = fmaf(bh(p1), v1.y, a1);
    a1 = fmaf(bl(q1), v1.z, a1); a1 = fmaf(bh(q1), v1.w, a1);
    a2 = fmaf(bl(p2), v2.x, a2); a2 = fmaf(bh(p2), v2.y, a2);
    a2 = fmaf(bl(q2), v2.z, a2); a2 = fmaf(bh(q2), v2.w, a2);
    a3 = fmaf(bl(p3), v3.x, a3); a3 = fmaf(bh(p3), v3.y, a3);
    a3 = fmaf(bl(q3), v3.z, a3); a3 = fmaf(bh(q3), v3.w, a3);
  }
  return (a0 + a1) + (a2 + a3);
}

// dot over 4*n4 elements, f32 weights streamed from global
__device__ __forceinline__ float dotgf(const float* row, const float* x, int n4) {
  float a = 0.f;
  for (int i = 0; i < n4; ++i) {
    float4 w = ((const float4*)row)[i];
    float4 xv = ((const float4*)x)[i];
    a = fmaf(w.x, xv.x, a);
    a = fmaf(w.y, xv.y, a);
    a = fmaf(w.z, xv.z, a);
    a = fmaf(w.w, xv.w, a);
  }
  return a;
}

// ---------------- prep kernels (gi_emb precompute) ----------------
__global__ void prep_enc(const float* __restrict__ emb, const int* __restrict__ seq,
                         const float* __restrict__ Wih, const float* __restrict__ bih,
                         float* __restrict__ giE)
{
  __shared__ __align__(16) float sx[64];
  const int it = blockIdx.x, t = threadIdx.x;
  if (t < 64) sx[t] = emb[(size_t)seq[it]*64 + t];
  __syncthreads();
  if (t < 192) giE[it*192 + t] = bih[t] + dotgf(Wih + (size_t)t*128, sx, 16);
}

__global__ void prep_dec(const float* __restrict__ emb2, const int* __restrict__ seq3,
                         const float* __restrict__ Wih, const float* __restrict__ bih,
                         float* __restrict__ giE)
{
  __shared__ __align__(16) float sx[64];
  const int it = blockIdx.x, t = threadIdx.x;
  const int tok = (it == 0) ? 136 : seq3[it-1];
  if (t < 64) sx[t] = emb2[(size_t)tok*64 + t];
  __syncthreads();
  if (t < 384) giE[it*384 + t] = bih[t] + dotgf(Wih + (size_t)t*192, sx, 16);
}

// ---------------- pack: dec Whh^T + ifw^T, bf16-pair [k2][r] ----------------
//  pk u32 layout: [0,24576) Whh^T (r<384, k2<64) ; [24576,33280) ifw^T (r<136, k2<64)
__global__ void pack_weights(const float* __restrict__ dWhh, const float* __restrict__ ifwW,
                             float* __restrict__ pk)
{
  const int i = blockIdx.x * 256 + threadIdx.x;
  u32* pku = (u32*)pk;
  if (i < 24576) {
    int r = i >> 6, k2 = i & 63;
    pku[k2*384 + r] = pk2(dWhh[r*128 + 2*k2], dWhh[r*128 + 2*k2 + 1]);
  } else if (i < 33280) {
    int p = i - 24576;
    int r = p >> 6, k2 = p & 63;
    pku[24576 + k2*136 + r] = pk2(ifwW[r*128 + 2*k2], ifwW[r*128 + 2*k2 + 1]);
  }
}

// ---------------- encoder: 512 sequential DNC steps, 1 block per encoder ----------------
// 6 barriers/step, zero steady-state global traffic, weights bf16 in registers (<=64 u32).
// stout per encoder (1440 f32):
//  [0,64) h | [64,128) lr | [128,144) rw | [144,160) mem norms | [160,1184) mem | [1184,1440) link
__global__ __launch_bounds__(512) void enc_kernel(
    const float* __restrict__ Wih1, const float* __restrict__ Whh1, const float* __restrict__ bhh1,
    const float* __restrict__ iW1, const float* __restrict__ ib1,
    const float* __restrict__ Wih2, const float* __restrict__ Whh2, const float* __restrict__ bhh2,
    const float* __restrict__ iW2, const float* __restrict__ ib2,
    const float* __restrict__ giE_all, float* __restrict__ stout)
{
  __shared__ __align__(16) float s_giE[64*192];   // 64-step gi_emb chunk (49 KB)
  __shared__ __align__(16) float s_h[64];
  __shared__ __align__(16) float s_hc[64];
  __shared__ __align__(16) float s_lr[64];
  __shared__ float s_gi[192];
  __shared__ float s_ghb[2][192];                 // gh pipeline (double buffer)
  __shared__ float s_xi[264];
  __shared__ __align__(16) float s_mem[16][64];
  __shared__ float s_link[16][16];
  __shared__ float s_prec[2][16];
  __shared__ float s_rw[16], s_ww[16], s_usage[16];
  __shared__ float s_norm[16], s_sim[16], s_fw[16];
  __shared__ float s_sc[8]; // 0:rs 1:ws 3:ag 4:wg 5..7:rm
  __shared__ float s_wkn, s_rkn;

  const int t = threadIdx.x;
  const int e = blockIdx.x;
  const float* Wih = e ? Wih2 : Wih1;
  const float* Whh = e ? Whh2 : Whh1;
  const float* bhh = e ? bhh2 : bhh1;
  const float* iW  = e ? iW2  : iW1;
  const float* ib  = e ? ib2  : ib1;
  const float* giE = giE_all + (size_t)e * 512 * 192;

  // register weights: wA = gi rows (t<192); w2 = xi rows (t<264) OR gh rows (264<=t<456)
  u32 wA[32], w2[32];
  float b2 = 0.f;
  if (t < 192) ldrow64pk(wA, Wih + (size_t)t*128 + 64);
  if (t < 264)      { ldrow64pk(w2, iW + (size_t)t*64);        b2 = ib[t]; }
  else if (t < 456) { ldrow64pk(w2, Whh + (size_t)(t-264)*64); b2 = bhh[t-264]; }

  if (t < 192) s_ghb[0][t] = bhh[t];     // h0 = 0 -> gh(step0) = bhh
  if (t < 64) { s_h[t] = 0.f; s_lr[t] = 0.f; }
  if (t < 16) {
    s_rw[t] = DELTAF; s_ww[t] = DELTAF; s_usage[t] = 0.f; s_norm[t] = 0.f;
    s_prec[0][t] = 0.f; s_prec[1][t] = 0.f;
  }
  { float* mf = &s_mem[0][0]; for (int i = t; i < 1024; i += 512) mf[i] = 0.f; }
  if (t < 256) (&s_link[0][0])[t] = 0.f;
  __syncthreads();

  int pb = 0;
  for (int it = 0; it < 512; ++it) {
    // ---- chunk refill (8x total, only global access) ----
    if ((it & 63) == 0) {
      const float4* src = (const float4*)(giE + it*192);
      float4* dst = (float4*)s_giE;
      for (int i = t; i < 3072; i += 512) dst[i] = src[i];
      __syncthreads();
    }
    // ---- P1: gi GEMV (reg weights, lr broadcast from LDS) ----
    if (t < 192) s_gi[t] = s_giE[(it & 63)*192 + t] + dotp64(wA, s_lr);
    __syncthreads();
    // ---- P2: GRU combine (gh from pipeline) ----
    if (t < 64) {
      const float* ghb = s_ghb[it & 1];
      float r = sigf(s_gi[t] + ghb[t]);
      float z = sigf(s_gi[64+t] + ghb[64+t]);
      float n = tanhf(s_gi[128+t] + r*ghb[128+t]);
      float h = (1.f - z)*n + z*s_h[t];
      s_h[t] = h;
      s_hc[t] = fminf(fmaxf(h, -CLIPF), CLIPF);
    }
    __syncthreads();
    // ---- P3: xi GEMV (t<264) || gh GEMV for NEXT step (264<=t<456) ----
    if (t < 264)      s_xi[t] = b2 + dotp64(w2, s_hc);
    else if (t < 456) s_ghb[(it + 1) & 1][t - 264] = b2 + dotp64(w2, s_h);
    __syncthreads();
    // ---- S1: write-key sim (raw) + key norms + usage + scalars ----
    {
      int m = t >> 5, l = t & 31;
      float wkl = tanhf(s_xi[65+l]);
      float wkh = tanhf(s_xi[65+32+l]);
      float p = fmaf(wkl, s_mem[m][l], wkh * s_mem[m][l+32]);
      p += __shfl_xor(p,1); p += __shfl_xor(p,2); p += __shfl_xor(p,4);
      p += __shfl_xor(p,8); p += __shfl_xor(p,16);
      if (l == 0) s_sim[m] = p;   // raw dot; normalized later
    }
    if (t >= 64 && t < 128) {
      int l = t - 64;                       // read-key norm
      float v = tanhf(s_xi[l]);
      float p = v*v;
      p += __shfl_xor(p,1); p += __shfl_xor(p,2); p += __shfl_xor(p,4);
      p += __shfl_xor(p,8); p += __shfl_xor(p,16); p += __shfl_xor(p,32);
      if (l == 0) s_rkn = sqrtf(p);
    } else if (t >= 128 && t < 192) {
      int l = t - 128;                      // write-key norm
      float v = tanhf(s_xi[65+l]);
      float p = v*v;
      p += __shfl_xor(p,1); p += __shfl_xor(p,2); p += __shfl_xor(p,4);
      p += __shfl_xor(p,8); p += __shfl_xor(p,16); p += __shfl_xor(p,32);
      if (l == 0) s_wkn = sqrtf(p);
    } else if (t >= 192 && t < 208) {
      int j = t - 192;                      // usage update (prev ww, prev rw, this fg)
      float fg = sigf(s_xi[258]);
      float u = s_usage[j];
      u = u + (1.f - u) * s_ww[j];
      u = u * (1.f - fg * s_rw[j]);
      s_usage[j] = u;
    } else if (t == 208) s_sc[0] = softplusf(s_xi[64]);
    else if (t == 209) s_sc[1] = softplusf(s_xi[129]);
    else if (t == 210) s_sc[3] = sigf(s_xi[259]);
    else if (t == 211) s_sc[4] = sigf(s_xi[260]);
    else if (t == 212) {
      float a = s_xi[261], b = s_xi[262], c = s_xi[263];
      float mx = fmaxf(a, fmaxf(b, c));
      float ea = expf(a-mx), eb = expf(b-mx), ec = expf(c-mx);
      float s = ea + eb + ec;
      s_sc[5] = ea/s; s_sc[6] = eb/s; s_sc[7] = ec/s;
    }
    __syncthreads();
    // ---- S23: per-wave redundant write-softmax/alloc; mem write; link+fw; prec ----
    {
      int row = t & 15;
      float x = s_sim[row] / ((s_norm[row] + DELTAF) * (s_wkn + DELTAF)) * s_sc[1];
      float mx = x;
      mx = fmaxf(mx, __shfl_xor(mx,1)); mx = fmaxf(mx, __shfl_xor(mx,2));
      mx = fmaxf(mx, __shfl_xor(mx,4)); mx = fmaxf(mx, __shfl_xor(mx,8));
      float ex = expf(x - mx);
      float sm = ex;
      sm += __shfl_xor(sm,1); sm += __shfl_xor(sm,2); sm += __shfl_xor(sm,4); sm += __shfl_xor(sm,8);
      float wcw = ex / sm;
      float um = DELTAF + (1.f - DELTAF) * s_usage[row];
      float prod = 1.f;
#pragma unroll
      for (int j = 0; j < 16; ++j) {
        float v = DELTAF + (1.f - DELTAF) * s_usage[j];
        bool before = (v < um) || ((v == um) && (j < row));  // stable argsort order
        prod *= before ? v : 1.f;
      }
      float alloc = (1.f - um) * prod;
      float wwv = s_sc[4] * (s_sc[3]*alloc + (1.f - s_sc[3])*wcw);
      float S = wwv;
      S += __shfl_xor(S,1); S += __shfl_xor(S,2); S += __shfl_xor(S,4); S += __shfl_xor(S,8);
      if (t < 16) s_ww[t] = wwv;            // for next step's usage update
      // memory write (all threads; m uniform per wave per q -> shfl broadcast)
#pragma unroll
      for (int q = 0; q < 2; ++q) {
        int idx = t + q*512;
        int m = idx >> 6, wi = idx & 63;
        float wwm = __shfl(wwv, m);
        float ev = sigf(s_xi[130+wi]);
        float wv = tanhf(s_xi[194+wi]);
        s_mem[m][wi] = s_mem[m][wi] * (1.f - wwm * ev) + wwm * wv;
      }
      if (t < 256) {                        // link + fw (waves 0..3)
        int i = t >> 4, j = t & 15;         // j == row
        float wwi = __shfl(wwv, i);
        float lv = (i == j) ? 0.f
                 : ((1.f - wwi - wwv) * s_link[i][j] + wwi * s_prec[pb][j]);
        s_link[i][j] = lv;
        float p = lv * s_rw[j];
        p += __shfl_xor(p,1); p += __shfl_xor(p,2); p += __shfl_xor(p,4); p += __shfl_xor(p,8);
        if (j == 0) s_fw[i] = p;
      } else if (t < 272) {                 // precedence (wave 4, lanes 0..15)
        int j = t - 256;                    // == row
        s_prec[pb^1][j] = (1.f - S) * s_prec[pb][j] + wwv;
      }
    }
    __syncthreads();
    // ---- S45: wave-0 mega-phase: read sim+norm+bw+softmax+rw+lr ----
    if (t < 64) {
      int l = t;
      int r4 = l >> 2, seg = l & 3;
      float p = 0.f, q = 0.f;
#pragma unroll
      for (int i = 0; i < 16; ++i) {
        int e = seg*16 + i;
        float rk = tanhf(s_xi[e]);
        float mv = s_mem[r4][e];
        p = fmaf(rk, mv, p);
        q = fmaf(mv, mv, q);
      }
      p += __shfl_xor(p,1); q += __shfl_xor(q,1);
      p += __shfl_xor(p,2); q += __shfl_xor(q,2);
      int row = l & 15;
      float simv  = __shfl(p, 4*row);
      float normv = sqrtf(__shfl(q, 4*row));
      float b = 0.f;                         // bw_row, partial over j
#pragma unroll
      for (int jj = 0; jj < 4; ++jj) {
        int j = (l >> 4)*4 + jj;
        b = fmaf(s_link[j][row], s_rw[j], b);
      }
      b += __shfl_xor(b,16); b += __shfl_xor(b,32);
      float x = simv / ((normv + DELTAF) * (s_rkn + DELTAF)) * s_sc[0];
      float mx = x;
      mx = fmaxf(mx, __shfl_xor(mx,1)); mx = fmaxf(mx, __shfl_xor(mx,2));
      mx = fmaxf(mx, __shfl_xor(mx,4)); mx = fmaxf(mx, __shfl_xor(mx,8));
      float ex = expf(x - mx);
      float sm = ex;
      sm += __shfl_xor(sm,1); sm += __shfl_xor(sm,2); sm += __shfl_xor(sm,4); sm += __shfl_xor(sm,8);
      float cw = ex / sm;
      float rwv = s_sc[5]*b + s_sc[6]*s_fw[row] + s_sc[7]*cw;
      if (l < 16) { s_rw[l] = rwv; s_norm[l] = normv; }   // norm carried to next step
      float a = 0.f;
#pragma unroll
      for (int m = 0; m < 16; ++m) a = fmaf(__shfl(rwv, m), s_mem[m][l], a);
      s_lr[l] = a;
    }
    pb ^= 1;
    __syncthreads();
  }

  float* so = stout + (size_t)e * 1440;
  if (t < 64) { so[t] = s_h[t]; so[64+t] = s_lr[t]; }
  if (t < 16) { so[128+t] = s_rw[t]; so[144+t] = s_norm[t]; }
  { const float* mf = &s_mem[0][0]; for (int i = t; i < 1024; i += 512) so[160+i] = mf[i]; }
  if (t < 256) so[1184+t] = (&s_link[0][0])[t];
}

// ---------------- decoder: 65 steps; Wih in regs, ifw in LDS, only Whh streamed ----------------
__global__ __launch_bounds__(512) void dec_kernel(
    const float* __restrict__ bhh, const float* __restrict__ ifwb,
    const float* __restrict__ dWih,
    const float* __restrict__ giE, const float* __restrict__ st,
    const float* __restrict__ pk, float* __restrict__ r12h)
{
  __shared__ u32 s_pIfw[8704];                 // ifw^T bf16-pair [k2][r] (34 KB)
  __shared__ __align__(16) float s_h[128];
  __shared__ __align__(16) float s_r12[128];
  __shared__ float s_gi[384], s_ghb[2][384], s_xi[136];
  __shared__ __align__(16) float s_mem[2][16][64];
  __shared__ float s_link[2][16][16];
  __shared__ float s_rw[2][16], s_norm[2][16];
  __shared__ float s_sim[2][16], s_fw[2][16], s_bw[2][16];
  __shared__ float s_rs[2], s_rkn[2];
  __shared__ float s_rm[2][3];
  __shared__ float s_bhh[384], s_ifwb[136];

  const int t = threadIdx.x;
  const u32* pWhh = (const u32*)pk;            // [k2*384 + r]
  const u32* pIfw = (const u32*)pk + 24576;    // [k2*136 + r]

  u32 w1[64];                                  // Wih-x row t (t<384), bf16
  if (t < 384) ldrow128pk(w1, dWih + (size_t)t*192 + 64);

  for (int i = t; i < 8704; i += 512) s_pIfw[i] = pIfw[i];
  if (t < 384) s_bhh[t]  = bhh[t];
  if (t < 136) s_ifwb[t] = ifwb[t];
  if (t < 64) {
    s_h[t]      = st[t];        s_h[64+t]   = st[1440+t];
    s_r12[t]    = st[64+t];     s_r12[64+t] = st[1440+64+t];
  }
  if (t < 16) {
    s_rw[0][t]   = st[128+t];   s_rw[1][t]   = st[1440+128+t];
    s_norm[0][t] = st[144+t];   s_norm[1][t] = st[1440+144+t];
  }
  for (int i = t; i < 1024; i += 512) {
    (&s_mem[0][0][0])[i] = st[160+i];
    (&s_mem[1][0][0])[i] = st[1440+160+i];
  }
  if (t < 256) {
    (&s_link[0][0][0])[t] = st[1184+t];
    (&s_link[1][0][0])[t] = st[1440+1184+t];
  }
  __syncthreads();

  // prologue: gh(step 0) = bhh + Whh . h0 (streamed)
  if (t < 384) {
    float a = 0.f;
#pragma unroll 8
    for (int k2 = 0; k2 < 64; ++k2) {
      u32 wp = pWhh[k2*384 + t];
      float2 xh = *(const float2*)&s_h[2*k2];
      a = fmaf(bl(wp), xh.x, fmaf(bh(wp), xh.y, a));
    }
    s_ghb[0][t] = s_bhh[t] + a;
  }
  __syncthreads();

  float gcur = (t < 384) ? giE[t] : 0.f;

  for (int it = 0; it < 65; ++it) {
    // ---- P1: gi (reg weights, x=[r1;r2]) ----
    if (t < 384) {
      int nx = (it + 1 < 65) ? (it + 1) : 64;
      float gn = giE[nx*384 + t];
      s_gi[t] = gcur + dotp128(w1, s_r12);
      gcur = gn;
    }
    __syncthreads();
    // ---- P2: GRU (H=128), gh from pipeline ----
    if (t < 128) {
      const float* ghb = s_ghb[it & 1];
      float r = sigf(s_gi[t] + ghb[t]);
      float z = sigf(s_gi[128+t] + ghb[128+t]);
      float n = tanhf(s_gi[256+t] + r*ghb[256+t]);
      s_h[t] = (1.f - z)*n + z*s_h[t];
    }
    __syncthreads();
    // ---- P3: gh(next) streamed (t<384) || xi from LDS (t>=384) ----
    if (t < 384) {
      float a = 0.f;
#pragma unroll 8
      for (int k2 = 0; k2 < 64; ++k2) {
        u32 wp = pWhh[k2*384 + t];
        float2 xh = *(const float2*)&s_h[2*k2];
        a = fmaf(bl(wp), xh.x, fmaf(bh(wp), xh.y, a));
      }
      s_ghb[(it + 1) & 1][t] = s_bhh[t] + a;
    } else {
      int r0 = t - 384;
      float c0 = 0.f;
#pragma unroll 8
      for (int k2 = 0; k2 < 64; ++k2) {
        u32 u = s_pIfw[k2*136 + r0];
        float2 xh = *(const float2*)&s_h[2*k2];
        c0 = fmaf(bl(u), xh.x, fmaf(bh(u), xh.y, c0));
      }
      s_xi[r0] = s_ifwb[r0] + c0;
      if (r0 < 8) {
        int r1 = 128 + r0;
        float c1 = 0.f;
#pragma unroll 8
        for (int k2 = 0; k2 < 64; ++k2) {
          u32 u = s_pIfw[k2*136 + r1];
          float2 xh = *(const float2*)&s_h[2*k2];
          c1 = fmaf(bl(u), xh.x, fmaf(bh(u), xh.y, c1));
        }
        s_xi[r1] = s_ifwb[r1] + c1;
      }
    }
    __syncthreads();
    // ---- S1: per-half sim (raw) + rk norm + fw/bw + scalars ----
    {
      int half = t >> 8, u = t & 255;
      int m = u >> 4, l = u & 15;
      float p = 0.f;
#pragma unroll
      for (int i = 0; i < 4; ++i) {
        float rk = tanhf(s_xi[half*64 + l*4 + i]);
        p = fmaf(rk, s_mem[half][m][l*4+i], p);
      }
      p += __shfl_xor(p,1); p += __shfl_xor(p,2); p += __shfl_xor(p,4); p += __shfl_xor(p,8);
      if (l == 0) s_sim[half][m] = p;   // raw
      if (u < 64) {
        float v = tanhf(s_xi[half*64 + u]);
        float q = v*v;
        q += __shfl_xor(q,1); q += __shfl_xor(q,2); q += __shfl_xor(q,4);
        q += __shfl_xor(q,8); q += __shfl_xor(q,16); q += __shfl_xor(q,32);
        if (u == 0) s_rkn[half] = sqrtf(q);
      } else if (u < 80) {
        int i = u - 64;
        float a = 0.f;
#pragma unroll
        for (int j = 0; j < 16; ++j) a = fmaf(s_link[half][i][j], s_rw[half][j], a);
        s_fw[half][i] = a;
      } else if (u < 96) {
        int i = u - 80;
        float a = 0.f;
#pragma unroll
        for (int j = 0; j < 16; ++j) a = fmaf(s_link[half][j][i], s_rw[half][j], a);
        s_bw[half][i] = a;
      } else if (u == 96) {
        s_rs[half] = softplusf(s_xi[128 + half]);
        float a = s_xi[130 + half*3], b = s_xi[131 + half*3], c = s_xi[132 + half*3];
        float mx = fmaxf(a, fmaxf(b, c));
        float ea = expf(a-mx), eb = expf(b-mx), ec = expf(c-mx);
        float s = ea+eb+ec;
        s_rm[half][0] = ea/s; s_rm[half][1] = eb/s; s_rm[half][2] = ec/s;
      }
    }
    __syncthreads();
    // ---- S2: per-half softmax + rw + read vector; h store for deferred logits ----
    if (t < 128) {
      int half = t >> 6, lane = t & 63;
      float rwv = 0.f;
      if (lane < 16) {
        float x = s_sim[half][lane] / ((s_norm[half][lane] + DELTAF)*(s_rkn[half] + DELTAF)) * s_rs[half];
        float mx = x;
        mx = fmaxf(mx, __shfl_xor(mx,1)); mx = fmaxf(mx, __shfl_xor(mx,2));
        mx = fmaxf(mx, __shfl_xor(mx,4)); mx = fmaxf(mx, __shfl_xor(mx,8));
        float ex = expf(x - mx);
        float sm = ex;
        sm += __shfl_xor(sm,1); sm += __shfl_xor(sm,2); sm += __shfl_xor(sm,4); sm += __shfl_xor(sm,8);
        float cw = ex / sm;
        rwv = s_rm[half][0]*s_bw[half][lane] + s_rm[half][1]*s_fw[half][lane] + s_rm[half][2]*cw;
        s_rw[half][lane] = rwv;
      }
      float a = 0.f;
#pragma unroll
      for (int m = 0; m < 16; ++m) a = fmaf(__shfl(rwv, m), s_mem[half][m][t & 63], a);
      s_r12[half*64 + (t&63)] = a;
      r12h[it*256 + half*64 + (t&63)] = a;
    } else if (t < 256) {
      r12h[it*256 + t] = s_h[t - 128];
    }
    __syncthreads();
  }
}

// ---------------- deferred logits ----------------
__global__ void logits_kernel(
    const float* __restrict__ r2oW, const float* __restrict__ r2ob,
    const float* __restrict__ outW, const float* __restrict__ outb,
    const float* __restrict__ r12h, float* __restrict__ out)
{
  __shared__ __align__(16) float s_in[128];
  __shared__ __align__(16) float s_oh[128];
  const int it = blockIdx.x, t = threadIdx.x;
  if (t < 128) s_in[t] = r12h[it*256 + t];
  __syncthreads();
  if (t < 128) {
    float o = r2ob[t] + dotgf(r2oW + (size_t)t*128, s_in, 32);
    s_oh[t] = o + r12h[it*256 + 128 + t];
  }
  __syncthreads();
  if (t < 138) {
    out[it*138 + t] = outb[t] + dotgf(outW + (size_t)t*128, s_oh, 32);
  }
}

extern "C" void kernel_launch(void* const* d_in, const int* in_sizes, int n_in,
                              void* d_out, int out_size, void* d_ws, size_t ws_size,
                              hipStream_t stream) {
  (void)in_sizes; (void)n_in; (void)out_size; (void)ws_size;
  const float* emb0   = (const float*)d_in[0];
  const float* emb1   = (const float*)d_in[1];
  const float* emb2   = (const float*)d_in[2];
  const float* e1_Wih = (const float*)d_in[3];
  const float* e1_Whh = (const float*)d_in[4];
  const float* e1_bih = (const float*)d_in[5];
  const float* e1_bhh = (const float*)d_in[6];
  const float* e1_iW  = (const float*)d_in[7];
  const float* e1_ib  = (const float*)d_in[8];
  const float* e2_Wih = (const float*)d_in[9];
  const float* e2_Whh = (const float*)d_in[10];
  const float* e2_bih = (const float*)d_in[11];
  const float* e2_bhh = (const float*)d_in[12];
  const float* e2_iW  = (const float*)d_in[13];
  const float* e2_ib  = (const float*)d_in[14];
  const float* dWih   = (const float*)d_in[15];
  const float* dWhh   = (const float*)d_in[16];
  const float* dbih   = (const float*)d_in[17];
  const float* dbhh   = (const float*)d_in[18];
  const float* ifwW   = (const float*)d_in[19];
  const float* ifwb   = (const float*)d_in[20];
  const float* r2oW   = (const float*)d_in[21];
  const float* r2ob   = (const float*)d_in[22];
  const float* outW   = (const float*)d_in[23];
  const float* outb   = (const float*)d_in[24];
  const int* seq1     = (const int*)d_in[25];
  const int* seq2     = (const int*)d_in[26];
  const int* seq3     = (const int*)d_in[27];

  float* ws   = (float*)d_ws;
  float* giE1 = ws;                    // 512*192 = 98304
  float* giE2 = giE1 + 98304;          // 98304 (contiguous with giE1)
  float* giEd = giE2 + 98304;          // 65*384 = 24960
  float* st   = giEd + 24960;          // 2*1440 = 2880
  float* r12h = st + 2880;             // 65*256 = 16640
  float* pkw  = r12h + 16640;          // 33280 u32 packed (dec Whh + ifw)

  prep_enc<<<512, 192, 0, stream>>>(emb0, seq1, e1_Wih, e1_bih, giE1);
  prep_enc<<<512, 192, 0, stream>>>(emb1, seq2, e2_Wih, e2_bih, giE2);
  prep_dec<<<65, 384, 0, stream>>>(emb2, seq3, dWih, dbih, giEd);
  pack_weights<<<(33280 + 255) / 256, 256, 0, stream>>>(dWhh, ifwW, pkw);
  enc_kernel<<<2, 512, 0, stream>>>(e1_Wih, e1_Whh, e1_bhh, e1_iW, e1_ib,
                                    e2_Wih, e2_Whh, e2_bhh, e2_iW, e2_ib, giE1, st);
  dec_kernel<<<1, 512, 0, stream>>>(dbhh, ifwb, dWih, giEd, st, pkw, r12h);
  logits_kernel<<<65, 256, 0, stream>>>(r2oW, r2ob, outW, outb, r12h, (float*)d_out);
}

// Round 8
// 3369.547 us; speedup vs baseline: 1.6549x; 1.1145x over previous
//
#include <hip/hip_runtime.h>
#include <hip/hip_bf16.h>
#include <stdint.h>

typedef uint32_t u32;

#define DELTAF 1e-6f
#define CLIPF 20.0f

__device__ __forceinline__ float bl(u32 u) { return __uint_as_float(u << 16); }
__device__ __forceinline__ float bh(u32 u) { return __uint_as_float(u & 0xffff0000u); }
__device__ __forceinline__ float sigf(float x) { return 1.f / (1.f + expf(-x)); }
__device__ __forceinline__ float softplusf(float x) { return fmaxf(x, 0.f) + log1pf(expf(-fabsf(x))); }
__device__ __forceinline__ u32 f2b(float f) {
  u32 b = __float_as_uint(f);
  return (b + 0x7fffu + ((b >> 16) & 1u)) >> 16;
}
__device__ __forceinline__ u32 pk2(float a, float b) { return f2b(a) | (f2b(b) << 16); }

// load 64 consecutive f32 -> bf16 RNE, pack into 32 u32 (registers)
__device__ __forceinline__ void ldrow64pk(u32* w, const float* p) {
  const float4* q = (const float4*)p;
#pragma unroll
  for (int i = 0; i < 16; ++i) {
    float4 v = q[i];
    w[2*i]   = pk2(v.x, v.y);
    w[2*i+1] = pk2(v.z, v.w);
  }
}

// load 128 consecutive f32 -> bf16 RNE, pack pairs into 64 u32
__device__ __forceinline__ void ldrow128pk(u32* w, const float* p) {
  const float4* q = (const float4*)p;
#pragma unroll
  for (int i = 0; i < 32; ++i) {
    float4 v = q[i];
    w[2*i]   = pk2(v.x, v.y);
    w[2*i+1] = pk2(v.z, v.w);
  }
}

// 64-long dot, packed bf16 weights (32 u32), x from LDS (broadcast reads)
__device__ __forceinline__ float dotp64(const u32* w, const float* x) {
  float a0 = 0.f, a1 = 0.f;
#pragma unroll
  for (int i = 0; i < 8; ++i) {
    float4 v0 = ((const float4*)x)[2*i+0];
    float4 v1 = ((const float4*)x)[2*i+1];
    u32 p0 = w[4*i+0], q0 = w[4*i+1], p1 = w[4*i+2], q1 = w[4*i+3];
    a0 = fmaf(bl(p0), v0.x, a0); a0 = fmaf(bh(p0), v0.y, a0);
    a0 = fmaf(bl(q0), v0.z, a0); a0 = fmaf(bh(q0), v0.w, a0);
    a1 = fmaf(bl(p1), v1.x, a1); a1 = fmaf(bh(p1), v1.y, a1);
    a1 = fmaf(bl(q1), v1.z, a1); a1 = fmaf(bh(q1), v1.w, a1);
  }
  return a0 + a1;
}

// 128-long dot, packed bf16 weights in regs, x from LDS
__device__ __forceinline__ float dotp128(const u32* w, const float* x) {
  float a0 = 0.f, a1 = 0.f, a2 = 0.f, a3 = 0.f;
#pragma unroll
  for (int i = 0; i < 8; ++i) {
    float4 v0 = ((const float4*)x)[4*i+0];
    float4 v1 = ((const float4*)x)[4*i+1];
    float4 v2 = ((const float4*)x)[4*i+2];
    float4 v3 = ((const float4*)x)[4*i+3];
    u32 p0 = w[8*i+0], q0 = w[8*i+1], p1 = w[8*i+2], q1 = w[8*i+3];
    u32 p2 = w[8*i+4], q2 = w[8*i+5], p3 = w[8*i+6], q3 = w[8*i+7];
    a0 = fmaf(bl(p0), v0.x, a0); a0 = fmaf(bh(p0), v0.y, a0);
    a0 = fmaf(bl(q0), v0.z, a0); a0 = fmaf(bh(q0), v0.w, a0);
    a1 = fmaf(bl(p1), v1.x, a1); a1 = fmaf(bh(p1), v1.y, a1);
    a1 = fmaf(bl(q1), v1.z, a1); a1 = fmaf(bh(q1), v1.w, a1);
    a2 = fmaf(bl(p2), v2.x, a2); a2 = fmaf(bh(p2), v2.y, a2);
    a2 = fmaf(bl(q2), v2.z, a2); a2 = fmaf(bh(q2), v2.w, a2);
    a3 = fmaf(bl(p3), v3.x, a3); a3 = fmaf(bh(p3), v3.y, a3);
    a3 = fmaf(bl(q3), v3.z, a3); a3 = fmaf(bh(q3), v3.w, a3);
  }
  return (a0 + a1) + (a2 + a3);
}

// dot over 4*n4 elements, f32 weights streamed from global
__device__ __forceinline__ float dotgf(const float* row, const float* x, int n4) {
  float a = 0.f;
  for (int i = 0; i < n4; ++i) {
    float4 w = ((const float4*)row)[i];
    float4 xv = ((const float4*)x)[i];
    a = fmaf(w.x, xv.x, a);
    a = fmaf(w.y, xv.y, a);
    a = fmaf(w.z, xv.z, a);
    a = fmaf(w.w, xv.w, a);
  }
  return a;
}

// ---------------- prep kernels (gi_emb precompute) ----------------
__global__ void prep_enc(const float* __restrict__ emb, const int* __restrict__ seq,
                         const float* __restrict__ Wih, const float* __restrict__ bih,
                         float* __restrict__ giE)
{
  __shared__ __align__(16) float sx[64];
  const int it = blockIdx.x, t = threadIdx.x;
  if (t < 64) sx[t] = emb[(size_t)seq[it]*64 + t];
  __syncthreads();
  if (t < 192) giE[it*192 + t] = bih[t] + dotgf(Wih + (size_t)t*128, sx, 16);
}

__global__ void prep_dec(const float* __restrict__ emb2, const int* __restrict__ seq3,
                         const float* __restrict__ Wih, const float* __restrict__ bih,
                         float* __restrict__ giE)
{
  __shared__ __align__(16) float sx[64];
  const int it = blockIdx.x, t = threadIdx.x;
  const int tok = (it == 0) ? 136 : seq3[it-1];
  if (t < 64) sx[t] = emb2[(size_t)tok*64 + t];
  __syncthreads();
  if (t < 384) giE[it*384 + t] = bih[t] + dotgf(Wih + (size_t)t*192, sx, 16);
}

// ---------------- pack: dec Whh^T + ifw^T, bf16-pair [k2][r] ----------------
//  pk u32 layout: [0,24576) Whh^T (r<384, k2<64) ; [24576,33280) ifw^T (r<136, k2<64)
__global__ void pack_weights(const float* __restrict__ dWhh, const float* __restrict__ ifwW,
                             float* __restrict__ pk)
{
  const int i = blockIdx.x * 256 + threadIdx.x;
  u32* pku = (u32*)pk;
  if (i < 24576) {
    int r = i >> 6, k2 = i & 63;
    pku[k2*384 + r] = pk2(dWhh[r*128 + 2*k2], dWhh[r*128 + 2*k2 + 1]);
  } else if (i < 33280) {
    int p = i - 24576;
    int r = p >> 6, k2 = p & 63;
    pku[24576 + k2*136 + r] = pk2(ifwW[r*128 + 2*k2], ifwW[r*128 + 2*k2 + 1]);
  }
}

// ---------------- encoder: 512 sequential DNC steps, 1 block per encoder ----------------
// 6 barriers/step, zero steady-state global traffic, bf16 weights in registers,
// s_mem padded [16][65] (bank-conflict-free), activations hoisted into S1.
// stout per encoder (1440 f32):
//  [0,64) h | [64,128) lr | [128,144) rw | [144,160) mem norms | [160,1184) mem | [1184,1440) link
__global__ __launch_bounds__(512) void enc_kernel(
    const float* __restrict__ Wih1, const float* __restrict__ Whh1, const float* __restrict__ bhh1,
    const float* __restrict__ iW1, const float* __restrict__ ib1,
    const float* __restrict__ Wih2, const float* __restrict__ Whh2, const float* __restrict__ bhh2,
    const float* __restrict__ iW2, const float* __restrict__ ib2,
    const float* __restrict__ giE_all, float* __restrict__ stout)
{
  __shared__ __align__(16) float s_giE[64*192];   // 64-step gi_emb chunk (49 KB)
  __shared__ __align__(16) float s_h[64];
  __shared__ __align__(16) float s_hc[64];
  __shared__ __align__(16) float s_lr[64];
  __shared__ float s_gi[192];
  __shared__ float s_ghb[2][192];                 // gh pipeline (double buffer)
  __shared__ float s_xi[264];
  __shared__ float s_mem[16][65];                 // PADDED: stride 65 -> conflict-free
  __shared__ float s_link[16][16];
  __shared__ float s_prec[2][16];
  __shared__ float s_rw[16], s_ww[16], s_usage[16];
  __shared__ float s_norm[16], s_sim[16], s_fw[16];
  __shared__ float s_rk[64], s_ev[64], s_wv[64];  // hoisted activations
  __shared__ float s_sc[8]; // 0:rs 1:ws 3:ag 4:wg 5..7:rm
  __shared__ float s_wkn, s_rkn;

  const int t = threadIdx.x;
  const int e = blockIdx.x;
  const float* Wih = e ? Wih2 : Wih1;
  const float* Whh = e ? Whh2 : Whh1;
  const float* bhh = e ? bhh2 : bhh1;
  const float* iW  = e ? iW2  : iW1;
  const float* ib  = e ? ib2  : ib1;
  const float* giE = giE_all + (size_t)e * 512 * 192;

  // register weights: wA = gi rows (t<192); w2 = xi rows (t<264) OR gh rows (264<=t<456)
  u32 wA[32], w2[32];
  float b2 = 0.f;
  if (t < 192) ldrow64pk(wA, Wih + (size_t)t*128 + 64);
  if (t < 264)      { ldrow64pk(w2, iW + (size_t)t*64);        b2 = ib[t]; }
  else if (t < 456) { ldrow64pk(w2, Whh + (size_t)(t-264)*64); b2 = bhh[t-264]; }

  if (t < 192) s_ghb[0][t] = bhh[t];     // h0 = 0 -> gh(step0) = bhh
  if (t < 64) { s_h[t] = 0.f; s_lr[t] = 0.f; }
  if (t < 16) {
    s_rw[t] = DELTAF; s_ww[t] = DELTAF; s_usage[t] = 0.f; s_norm[t] = 0.f;
    s_prec[0][t] = 0.f; s_prec[1][t] = 0.f;
  }
  for (int i = t; i < 1040; i += 512) { int m = i / 65, c = i % 65; s_mem[m][c] = 0.f; }
  if (t < 256) (&s_link[0][0])[t] = 0.f;
  __syncthreads();

  int pb = 0;
  for (int it = 0; it < 512; ++it) {
    // ---- chunk refill (8x total, only global access) ----
    if ((it & 63) == 0) {
      const float4* src = (const float4*)(giE + it*192);
      float4* dst = (float4*)s_giE;
      for (int i = t; i < 3072; i += 512) dst[i] = src[i];
      __syncthreads();
    }
    // ---- P1: gi GEMV (reg weights, lr broadcast from LDS) ----
    if (t < 192) s_gi[t] = s_giE[(it & 63)*192 + t] + dotp64(wA, s_lr);
    __syncthreads();
    // ---- P2: GRU combine (gh from pipeline) ----
    if (t < 64) {
      const float* ghb = s_ghb[it & 1];
      float r = sigf(s_gi[t] + ghb[t]);
      float z = sigf(s_gi[64+t] + ghb[64+t]);
      float n = tanhf(s_gi[128+t] + r*ghb[128+t]);
      float h = (1.f - z)*n + z*s_h[t];
      s_h[t] = h;
      s_hc[t] = fminf(fmaxf(h, -CLIPF), CLIPF);
    }
    __syncthreads();
    // ---- P3: xi GEMV (t<264) || gh GEMV for NEXT step (264<=t<456) ----
    if (t < 264)      s_xi[t] = b2 + dotp64(w2, s_hc);
    else if (t < 456) s_ghb[(it + 1) & 1][t - 264] = b2 + dotp64(w2, s_h);
    __syncthreads();
    // ---- S1: write-key sim (raw, all threads) + hoisted activations + norms + usage + scalars ----
    {
      int m = t >> 5, l = t & 31;
      float wkl = tanhf(s_xi[65+l]);
      float wkh = tanhf(s_xi[65+32+l]);
      float p = fmaf(wkl, s_mem[m][l], wkh * s_mem[m][l+32]);
      p += __shfl_xor(p,1); p += __shfl_xor(p,2); p += __shfl_xor(p,4);
      p += __shfl_xor(p,8); p += __shfl_xor(p,16);
      if (l == 0) s_sim[m] = p;   // raw dot; normalized later
    }
    if (t < 64) {
      s_ev[t] = sigf(s_xi[130+t]);
    } else if (t < 128) {
      int l = t - 64;                       // read-key norm
      float v = tanhf(s_xi[l]);
      float p = v*v;
      p += __shfl_xor(p,1); p += __shfl_xor(p,2); p += __shfl_xor(p,4);
      p += __shfl_xor(p,8); p += __shfl_xor(p,16); p += __shfl_xor(p,32);
      if (l == 0) s_rkn = sqrtf(p);
    } else if (t < 192) {
      int l = t - 128;                      // write-key norm
      float v = tanhf(s_xi[65+l]);
      float p = v*v;
      p += __shfl_xor(p,1); p += __shfl_xor(p,2); p += __shfl_xor(p,4);
      p += __shfl_xor(p,8); p += __shfl_xor(p,16); p += __shfl_xor(p,32);
      if (l == 0) s_wkn = sqrtf(p);
    } else if (t < 208) {
      int j = t - 192;                      // usage update (prev ww, prev rw, this fg)
      float fg = sigf(s_xi[258]);
      float u = s_usage[j];
      u = u + (1.f - u) * s_ww[j];
      u = u * (1.f - fg * s_rw[j]);
      s_usage[j] = u;
    } else if (t == 208) s_sc[0] = softplusf(s_xi[64]);
    else if (t == 209) s_sc[1] = softplusf(s_xi[129]);
    else if (t == 210) s_sc[3] = sigf(s_xi[259]);
    else if (t == 211) s_sc[4] = sigf(s_xi[260]);
    else if (t == 212) {
      float a = s_xi[261], b = s_xi[262], c = s_xi[263];
      float mx = fmaxf(a, fmaxf(b, c));
      float ea = expf(a-mx), eb = expf(b-mx), ec = expf(c-mx);
      float s = ea + eb + ec;
      s_sc[5] = ea/s; s_sc[6] = eb/s; s_sc[7] = ec/s;
    } else if (t >= 384 && t < 448) {
      int l = t - 384;                      // hoisted read-key tanh
      s_rk[l] = tanhf(s_xi[l]);
    } else if (t >= 448) {
      int l = t - 448;                      // hoisted write-vector tanh
      s_wv[l] = tanhf(s_xi[194+l]);
    }
    __syncthreads();
    // ---- S23: per-wave redundant write-softmax/alloc; mem write; link+fw; prec ----
    {
      int row = t & 15;
      float x = s_sim[row] / ((s_norm[row] + DELTAF) * (s_wkn + DELTAF)) * s_sc[1];
      float mx = x;
      mx = fmaxf(mx, __shfl_xor(mx,1)); mx = fmaxf(mx, __shfl_xor(mx,2));
      mx = fmaxf(mx, __shfl_xor(mx,4)); mx = fmaxf(mx, __shfl_xor(mx,8));
      float ex = expf(x - mx);
      float sm = ex;
      sm += __shfl_xor(sm,1); sm += __shfl_xor(sm,2); sm += __shfl_xor(sm,4); sm += __shfl_xor(sm,8);
      float wcw = ex / sm;
      float um = DELTAF + (1.f - DELTAF) * s_usage[row];
      float prod = 1.f;
#pragma unroll
      for (int j = 0; j < 16; ++j) {
        float v = DELTAF + (1.f - DELTAF) * s_usage[j];
        bool before = (v < um) || ((v == um) && (j < row));  // stable argsort order
        prod *= before ? v : 1.f;
      }
      float alloc = (1.f - um) * prod;
      float wwv = s_sc[4] * (s_sc[3]*alloc + (1.f - s_sc[3])*wcw);
      float S = wwv;
      S += __shfl_xor(S,1); S += __shfl_xor(S,2); S += __shfl_xor(S,4); S += __shfl_xor(S,8);
      if (t < 16) s_ww[t] = wwv;            // for next step's usage update
      // memory write (all threads; m uniform per wave per q -> shfl broadcast)
#pragma unroll
      for (int q = 0; q < 2; ++q) {
        int idx = t + q*512;
        int m = idx >> 6, wi = idx & 63;
        float wwm = __shfl(wwv, m);
        s_mem[m][wi] = s_mem[m][wi] * (1.f - wwm * s_ev[wi]) + wwm * s_wv[wi];
      }
      if (t < 256) {                        // link + fw (waves 0..3)
        int i = t >> 4, j = t & 15;         // j == row
        float wwi = __shfl(wwv, i);
        float lv = (i == j) ? 0.f
                 : ((1.f - wwi - wwv) * s_link[i][j] + wwi * s_prec[pb][j]);
        s_link[i][j] = lv;
        float p = lv * s_rw[j];
        p += __shfl_xor(p,1); p += __shfl_xor(p,2); p += __shfl_xor(p,4); p += __shfl_xor(p,8);
        if (j == 0) s_fw[i] = p;
      } else if (t < 272) {                 // precedence (wave 4, lanes 0..15)
        int j = t - 256;                    // == row
        s_prec[pb^1][j] = (1.f - S) * s_prec[pb][j] + wwv;
      }
    }
    __syncthreads();
    // ---- S45: wave-0 mega-phase: read sim+norm+bw+softmax+rw+lr (conflict-free, no tanh) ----
    if (t < 64) {
      int l = t;
      int r4 = l >> 2, seg = l & 3;
      float p = 0.f, q = 0.f;
#pragma unroll
      for (int i = 0; i < 16; ++i) {
        int el = seg*16 + i;
        float mv = s_mem[r4][el];
        p = fmaf(s_rk[el], mv, p);
        q = fmaf(mv, mv, q);
      }
      p += __shfl_xor(p,1); q += __shfl_xor(q,1);
      p += __shfl_xor(p,2); q += __shfl_xor(q,2);
      int row = l & 15;
      float simv  = __shfl(p, 4*row);
      float normv = sqrtf(__shfl(q, 4*row));
      float b = 0.f;                         // bw_row, partial over j
#pragma unroll
      for (int jj = 0; jj < 4; ++jj) {
        int j = (l >> 4)*4 + jj;
        b = fmaf(s_link[j][row], s_rw[j], b);
      }
      b += __shfl_xor(b,16); b += __shfl_xor(b,32);
      float x = simv / ((normv + DELTAF) * (s_rkn + DELTAF)) * s_sc[0];
      float mx = x;
      mx = fmaxf(mx, __shfl_xor(mx,1)); mx = fmaxf(mx, __shfl_xor(mx,2));
      mx = fmaxf(mx, __shfl_xor(mx,4)); mx = fmaxf(mx, __shfl_xor(mx,8));
      float ex = expf(x - mx);
      float sm = ex;
      sm += __shfl_xor(sm,1); sm += __shfl_xor(sm,2); sm += __shfl_xor(sm,4); sm += __shfl_xor(sm,8);
      float cw = ex / sm;
      float rwv = s_sc[5]*b + s_sc[6]*s_fw[row] + s_sc[7]*cw;
      if (l < 16) { s_rw[l] = rwv; s_norm[l] = normv; }   // norm carried to next step
      float a = 0.f;
#pragma unroll
      for (int m = 0; m < 16; ++m) a = fmaf(__shfl(rwv, m), s_mem[m][l], a);
      s_lr[l] = a;
    }
    pb ^= 1;
    __syncthreads();
  }

  float* so = stout + (size_t)e * 1440;
  if (t < 64) { so[t] = s_h[t]; so[64+t] = s_lr[t]; }
  if (t < 16) { so[128+t] = s_rw[t]; so[144+t] = s_norm[t]; }
  for (int i = t; i < 1024; i += 512) { int m = i >> 6, c = i & 63; so[160+i] = s_mem[m][c]; }
  if (t < 256) so[1184+t] = (&s_link[0][0])[t];
}

// ---------------- decoder: 65 steps; Wih in regs, ifw in LDS, only Whh streamed ----------------
__global__ __launch_bounds__(512) void dec_kernel(
    const float* __restrict__ bhh, const float* __restrict__ ifwb,
    const float* __restrict__ dWih,
    const float* __restrict__ giE, const float* __restrict__ st,
    const float* __restrict__ pk, float* __restrict__ r12h)
{
  __shared__ u32 s_pIfw[8704];                 // ifw^T bf16-pair [k2][r] (34 KB)
  __shared__ __align__(16) float s_h[128];
  __shared__ __align__(16) float s_r12[128];
  __shared__ float s_gi[384], s_ghb[2][384], s_xi[136];
  __shared__ __align__(16) float s_mem[2][16][64];
  __shared__ float s_link[2][16][16];
  __shared__ float s_rw[2][16], s_norm[2][16];
  __shared__ float s_sim[2][16], s_fw[2][16], s_bw[2][16];
  __shared__ float s_rs[2], s_rkn[2];
  __shared__ float s_rm[2][3];
  __shared__ float s_bhh[384], s_ifwb[136];

  const int t = threadIdx.x;
  const u32* pWhh = (const u32*)pk;            // [k2*384 + r]
  const u32* pIfw = (const u32*)pk + 24576;    // [k2*136 + r]

  u32 w1[64];                                  // Wih-x row t (t<384), bf16
  if (t < 384) ldrow128pk(w1, dWih + (size_t)t*192 + 64);

  for (int i = t; i < 8704; i += 512) s_pIfw[i] = pIfw[i];
  if (t < 384) s_bhh[t]  = bhh[t];
  if (t < 136) s_ifwb[t] = ifwb[t];
  if (t < 64) {
    s_h[t]      = st[t];        s_h[64+t]   = st[1440+t];
    s_r12[t]    = st[64+t];     s_r12[64+t] = st[1440+64+t];
  }
  if (t < 16) {
    s_rw[0][t]   = st[128+t];   s_rw[1][t]   = st[1440+128+t];
    s_norm[0][t] = st[144+t];   s_norm[1][t] = st[1440+144+t];
  }
  for (int i = t; i < 1024; i += 512) {
    (&s_mem[0][0][0])[i] = st[160+i];
    (&s_mem[1][0][0])[i] = st[1440+160+i];
  }
  if (t < 256) {
    (&s_link[0][0][0])[t] = st[1184+t];
    (&s_link[1][0][0])[t] = st[1440+1184+t];
  }
  __syncthreads();

  // prologue: gh(step 0) = bhh + Whh . h0 (streamed)
  if (t < 384) {
    float a = 0.f;
#pragma unroll 8
    for (int k2 = 0; k2 < 64; ++k2) {
      u32 wp = pWhh[k2*384 + t];
      float2 xh = *(const float2*)&s_h[2*k2];
      a = fmaf(bl(wp), xh.x, fmaf(bh(wp), xh.y, a));
    }
    s_ghb[0][t] = s_bhh[t] + a;
  }
  __syncthreads();

  float gcur = (t < 384) ? giE[t] : 0.f;

  for (int it = 0; it < 65; ++it) {
    // ---- P1: gi (reg weights, x=[r1;r2]) ----
    if (t < 384) {
      int nx = (it + 1 < 65) ? (it + 1) : 64;
      float gn = giE[nx*384 + t];
      s_gi[t] = gcur + dotp128(w1, s_r12);
      gcur = gn;
    }
    __syncthreads();
    // ---- P2: GRU (H=128), gh from pipeline ----
    if (t < 128) {
      const float* ghb = s_ghb[it & 1];
      float r = sigf(s_gi[t] + ghb[t]);
      float z = sigf(s_gi[128+t] + ghb[128+t]);
      float n = tanhf(s_gi[256+t] + r*ghb[256+t]);
      s_h[t] = (1.f - z)*n + z*s_h[t];
    }
    __syncthreads();
    // ---- P3: gh(next) streamed (t<384) || xi from LDS (t>=384) ----
    if (t < 384) {
      float a = 0.f;
#pragma unroll 8
      for (int k2 = 0; k2 < 64; ++k2) {
        u32 wp = pWhh[k2*384 + t];
        float2 xh = *(const float2*)&s_h[2*k2];
        a = fmaf(bl(wp), xh.x, fmaf(bh(wp), xh.y, a));
      }
      s_ghb[(it + 1) & 1][t] = s_bhh[t] + a;
    } else {
      int r0 = t - 384;
      float c0 = 0.f;
#pragma unroll 8
      for (int k2 = 0; k2 < 64; ++k2) {
        u32 u = s_pIfw[k2*136 + r0];
        float2 xh = *(const float2*)&s_h[2*k2];
        c0 = fmaf(bl(u), xh.x, fmaf(bh(u), xh.y, c0));
      }
      s_xi[r0] = s_ifwb[r0] + c0;
      if (r0 < 8) {
        int r1 = 128 + r0;
        float c1 = 0.f;
#pragma unroll 8
        for (int k2 = 0; k2 < 64; ++k2) {
          u32 u = s_pIfw[k2*136 + r1];
          float2 xh = *(const float2*)&s_h[2*k2];
          c1 = fmaf(bl(u), xh.x, fmaf(bh(u), xh.y, c1));
        }
        s_xi[r1] = s_ifwb[r1] + c1;
      }
    }
    __syncthreads();
    // ---- S1: per-half sim (raw) + rk norm + fw/bw + scalars ----
    {
      int half = t >> 8, u = t & 255;
      int m = u >> 4, l = u & 15;
      float p = 0.f;
#pragma unroll
      for (int i = 0; i < 4; ++i) {
        float rk = tanhf(s_xi[half*64 + l*4 + i]);
        p = fmaf(rk, s_mem[half][m][l*4+i], p);
      }
      p += __shfl_xor(p,1); p += __shfl_xor(p,2); p += __shfl_xor(p,4); p += __shfl_xor(p,8);
      if (l == 0) s_sim[half][m] = p;   // raw
      if (u < 64) {
        float v = tanhf(s_xi[half*64 + u]);
        float q = v*v;
        q += __shfl_xor(q,1); q += __shfl_xor(q,2); q += __shfl_xor(q,4);
        q += __shfl_xor(q,8); q += __shfl_xor(q,16); q += __shfl_xor(q,32);
        if (u == 0) s_rkn[half] = sqrtf(q);
      } else if (u < 80) {
        int i = u - 64;
        float a = 0.f;
#pragma unroll
        for (int j = 0; j < 16; ++j) a = fmaf(s_link[half][i][j], s_rw[half][j], a);
        s_fw[half][i] = a;
      } else if (u < 96) {
        int i = u - 80;
        float a = 0.f;
#pragma unroll
        for (int j = 0; j < 16; ++j) a = fmaf(s_link[half][j][i], s_rw[half][j], a);
        s_bw[half][i] = a;
      } else if (u == 96) {
        s_rs[half] = softplusf(s_xi[128 + half]);
        float a = s_xi[130 + half*3], b = s_xi[131 + half*3], c = s_xi[132 + half*3];
        float mx = fmaxf(a, fmaxf(b, c));
        float ea = expf(a-mx), eb = expf(b-mx), ec = expf(c-mx);
        float s = ea+eb+ec;
        s_rm[half][0] = ea/s; s_rm[half][1] = eb/s; s_rm[half][2] = ec/s;
      }
    }
    __syncthreads();
    // ---- S2: per-half softmax + rw + read vector; h store for deferred logits ----
    if (t < 128) {
      int half = t >> 6, lane = t & 63;
      float rwv = 0.f;
      if (lane < 16) {
        float x = s_sim[half][lane] / ((s_norm[half][lane] + DELTAF)*(s_rkn[half] + DELTAF)) * s_rs[half];
        float mx = x;
        mx = fmaxf(mx, __shfl_xor(mx,1)); mx = fmaxf(mx, __shfl_xor(mx,2));
        mx = fmaxf(mx, __shfl_xor(mx,4)); mx = fmaxf(mx, __shfl_xor(mx,8));
        float ex = expf(x - mx);
        float sm = ex;
        sm += __shfl_xor(sm,1); sm += __shfl_xor(sm,2); sm += __shfl_xor(sm,4); sm += __shfl_xor(sm,8);
        float cw = ex / sm;
        rwv = s_rm[half][0]*s_bw[half][lane] + s_rm[half][1]*s_fw[half][lane] + s_rm[half][2]*cw;
        s_rw[half][lane] = rwv;
      }
      float a = 0.f;
#pragma unroll
      for (int m = 0; m < 16; ++m) a = fmaf(__shfl(rwv, m), s_mem[half][m][t & 63], a);
      s_r12[half*64 + (t&63)] = a;
      r12h[it*256 + half*64 + (t&63)] = a;
    } else if (t < 256) {
      r12h[it*256 + t] = s_h[t - 128];
    }
    __syncthreads();
  }
}

// ---------------- deferred logits ----------------
__global__ void logits_kernel(
    const float* __restrict__ r2oW, const float* __restrict__ r2ob,
    const float* __restrict__ outW, const float* __restrict__ outb,
    const float* __restrict__ r12h, float* __restrict__ out)
{
  __shared__ __align__(16) float s_in[128];
  __shared__ __align__(16) float s_oh[128];
  const int it = blockIdx.x, t = threadIdx.x;
  if (t < 128) s_in[t] = r12h[it*256 + t];
  __syncthreads();
  if (t < 128) {
    float o = r2ob[t] + dotgf(r2oW + (size_t)t*128, s_in, 32);
    s_oh[t] = o + r12h[it*256 + 128 + t];
  }
  __syncthreads();
  if (t < 138) {
    out[it*138 + t] = outb[t] + dotgf(outW + (size_t)t*128, s_oh, 32);
  }
}

extern "C" void kernel_launch(void* const* d_in, const int* in_sizes, int n_in,
                              void* d_out, int out_size, void* d_ws, size_t ws_size,
                              hipStream_t stream) {
  (void)in_sizes; (void)n_in; (void)out_size; (void)ws_size;
  const float* emb0   = (const float*)d_in[0];
  const float* emb1   = (const float*)d_in[1];
  const float* emb2   = (const float*)d_in[2];
  const float* e1_Wih = (const float*)d_in[3];
  const float* e1_Whh = (const float*)d_in[4];
  const float* e1_bih = (const float*)d_in[5];
  const float* e1_bhh = (const float*)d_in[6];
  const float* e1_iW  = (const float*)d_in[7];
  const float* e1_ib  = (const float*)d_in[8];
  const float* e2_Wih = (const float*)d_in[9];
  const float* e2_Whh = (const float*)d_in[10];
  const float* e2_bih = (const float*)d_in[11];
  const float* e2_bhh = (const float*)d_in[12];
  const float* e2_iW  = (const float*)d_in[13];
  const float* e2_ib  = (const float*)d_in[14];
  const float* dWih   = (const float*)d_in[15];
  const float* dWhh   = (const float*)d_in[16];
  const float* dbih   = (const float*)d_in[17];
  const float* dbhh   = (const float*)d_in[18];
  const float* ifwW   = (const float*)d_in[19];
  const float* ifwb   = (const float*)d_in[20];
  const float* r2oW   = (const float*)d_in[21];
  const float* r2ob   = (const float*)d_in[22];
  const float* outW   = (const float*)d_in[23];
  const float* outb   = (const float*)d_in[24];
  const int* seq1     = (const int*)d_in[25];
  const int* seq2     = (const int*)d_in[26];
  const int* seq3     = (const int*)d_in[27];

  float* ws   = (float*)d_ws;
  float* giE1 = ws;                    // 512*192 = 98304
  float* giE2 = giE1 + 98304;          // 98304 (contiguous with giE1)
  float* giEd = giE2 + 98304;          // 65*384 = 24960
  float* st   = giEd + 24960;          // 2*1440 = 2880
  float* r12h = st + 2880;             // 65*256 = 16640
  float* pkw  = r12h + 16640;          // 33280 u32 packed (dec Whh + ifw)

  prep_enc<<<512, 192, 0, stream>>>(emb0, seq1, e1_Wih, e1_bih, giE1);
  prep_enc<<<512, 192, 0, stream>>>(emb1, seq2, e2_Wih, e2_bih, giE2);
  prep_dec<<<65, 384, 0, stream>>>(emb2, seq3, dWih, dbih, giEd);
  pack_weights<<<(33280 + 255) / 256, 256, 0, stream>>>(dWhh, ifwW, pkw);
  enc_kernel<<<2, 512, 0, stream>>>(e1_Wih, e1_Whh, e1_bhh, e1_iW, e1_ib,
                                    e2_Wih, e2_Whh, e2_bhh, e2_iW, e2_ib, giE1, st);
  dec_kernel<<<1, 512, 0, stream>>>(dbhh, ifwb, dWih, giEd, st, pkw, r12h);
  logits_kernel<<<65, 256, 0, stream>>>(r2oW, r2ob, outW, outb, r12h, (float*)d_out);
}

// Round 11
// 2552.390 us; speedup vs baseline: 2.1847x; 1.3202x over previous
//
#include <hip/hip_runtime.h>
#include <hip/hip_bf16.h>
#include <stdint.h>

typedef uint32_t u32;

#define DELTAF 1e-6f
#define CLIPF 20.0f

__device__ __forceinline__ float bl(u32 u) { return __uint_as_float(u << 16); }
__device__ __forceinline__ float bh(u32 u) { return __uint_as_float(u & 0xffff0000u); }

// ---- fast transcendentals (f32 in/out, ~1e-7 rel err; deterministic) ----
__device__ __forceinline__ float fexp(float x) { return __builtin_amdgcn_exp2f(x * 1.4426950408889634f); }
__device__ __forceinline__ float frcp(float x) { return __builtin_amdgcn_rcpf(x); }
__device__ __forceinline__ float fsig(float x) { return frcp(1.f + fexp(-x)); }
__device__ __forceinline__ float ftanh(float x) {
  float xx = fminf(fmaxf(x, -15.f), 15.f);
  float t = __builtin_amdgcn_exp2f(xx * 2.8853900817779268f);  // e^(2x)
  return (t - 1.f) * frcp(t + 1.f);
}
__device__ __forceinline__ float softplusf(float x) { return fmaxf(x, 0.f) + log1pf(expf(-fabsf(x))); }

// f32 -> bf16 bits, RNE
__device__ __forceinline__ u32 f2b(float f) {
  u32 b = __float_as_uint(f);
  return (b + 0x7fffu + ((b >> 16) & 1u)) >> 16;
}
__device__ __forceinline__ u32 pk2(float a, float b) { return f2b(a) | (f2b(b) << 16); }

// ---- DPP reduction helpers (VALU-only, replace ds_bpermute shfl chains) ----
template<int CTRL>
__device__ __forceinline__ float dppf(float v) {
  return __int_as_float(__builtin_amdgcn_update_dpp(0, __float_as_int(v), CTRL, 0xf, 0xf, true));
}
// all-lanes sum/max within each 16-lane row (row_ror 8,4,2,1)
__device__ __forceinline__ float dsum16(float v) {
  v += dppf<0x128>(v); v += dppf<0x124>(v); v += dppf<0x122>(v); v += dppf<0x121>(v);
  return v;
}
__device__ __forceinline__ float dmax16(float v) {
  v = fmaxf(v, dppf<0x128>(v)); v = fmaxf(v, dppf<0x124>(v));
  v = fmaxf(v, dppf<0x122>(v)); v = fmaxf(v, dppf<0x121>(v));
  return v;
}
// all-lanes sum within each quad (quad_perm xor1, xor2)
__device__ __forceinline__ float dsum4(float v) {
  v += dppf<0xB1>(v); v += dppf<0x4E>(v);
  return v;
}
__device__ __forceinline__ float rdlane(float v, int lane) {
  return __int_as_float(__builtin_amdgcn_readlane(__float_as_int(v), lane));
}

// load 64 consecutive f32 -> bf16 RNE, pack into 32 u32 (registers)
__device__ __forceinline__ void ldrow64pk(u32* w, const float* p) {
  const float4* q = (const float4*)p;
#pragma unroll
  for (int i = 0; i < 16; ++i) {
    float4 v = q[i];
    w[2*i]   = pk2(v.x, v.y);
    w[2*i+1] = pk2(v.z, v.w);
  }
}

// load 128 consecutive f32 -> bf16 RNE, pack pairs into 64 u32
__device__ __forceinline__ void ldrow128pk(u32* w, const float* p) {
  const float4* q = (const float4*)p;
#pragma unroll
  for (int i = 0; i < 32; ++i) {
    float4 v = q[i];
    w[2*i]   = pk2(v.x, v.y);
    w[2*i+1] = pk2(v.z, v.w);
  }
}

// 64-long dot, packed bf16 weights (32 u32), x from LDS (broadcast reads)
__device__ __forceinline__ float dotp64(const u32* w, const float* x) {
  float a0 = 0.f, a1 = 0.f;
#pragma unroll
  for (int i = 0; i < 8; ++i) {
    float4 v0 = ((const float4*)x)[2*i+0];
    float4 v1 = ((const float4*)x)[2*i+1];
    u32 p0 = w[4*i+0], q0 = w[4*i+1], p1 = w[4*i+2], q1 = w[4*i+3];
    a0 = fmaf(bl(p0), v0.x, a0); a0 = fmaf(bh(p0), v0.y, a0);
    a0 = fmaf(bl(q0), v0.z, a0); a0 = fmaf(bh(q0), v0.w, a0);
    a1 = fmaf(bl(p1), v1.x, a1); a1 = fmaf(bh(p1), v1.y, a1);
    a1 = fmaf(bl(q1), v1.z, a1); a1 = fmaf(bh(q1), v1.w, a1);
  }
  return a0 + a1;
}

// 128-long dot, packed bf16 weights in regs, x from LDS
__device__ __forceinline__ float dotp128(const u32* w, const float* x) {
  float a0 = 0.f, a1 = 0.f, a2 = 0.f, a3 = 0.f;
#pragma unroll
  for (int i = 0; i < 8; ++i) {
    float4 v0 = ((const float4*)x)[4*i+0];
    float4 v1 = ((const float4*)x)[4*i+1];
    float4 v2 = ((const float4*)x)[4*i+2];
    float4 v3 = ((const float4*)x)[4*i+3];
    u32 p0 = w[8*i+0], q0 = w[8*i+1], p1 = w[8*i+2], q1 = w[8*i+3];
    u32 p2 = w[8*i+4], q2 = w[8*i+5], p3 = w[8*i+6], q3 = w[8*i+7];
    a0 = fmaf(bl(p0), v0.x, a0); a0 = fmaf(bh(p0), v0.y, a0);
    a0 = fmaf(bl(q0), v0.z, a0); a0 = fmaf(bh(q0), v0.w, a0);
    a1 = fmaf(bl(p1), v1.x, a1); a1 = fmaf(bh(p1), v1.y, a1);
    a1 = fmaf(bl(q1), v1.z, a1); a1 = fmaf(bh(q1), v1.w, a1);
    a2 = fmaf(bl(p2), v2.x, a2); a2 = fmaf(bh(p2), v2.y, a2);
    a2 = fmaf(bl(q2), v2.z, a2); a2 = fmaf(bh(q2), v2.w, a2);
    a3 = fmaf(bl(p3), v3.x, a3); a3 = fmaf(bh(p3), v3.y, a3);
    a3 = fmaf(bl(q3), v3.z, a3); a3 = fmaf(bh(q3), v3.w, a3);
  }
  return (a0 + a1) + (a2 + a3);
}

// dot over 4*n4 elements, f32 weights streamed from global
__device__ __forceinline__ float dotgf(const float* row, const float* x, int n4) {
  float a = 0.f;
  for (int i = 0; i < n4; ++i) {
    float4 w = ((const float4*)row)[i];
    float4 xv = ((const float4*)x)[i];
    a = fmaf(w.x, xv.x, a);
    a = fmaf(w.y, xv.y, a);
    a = fmaf(w.z, xv.z, a);
    a = fmaf(w.w, xv.w, a);
  }
  return a;
}

// ---------------- prep kernels (gi_emb precompute) ----------------
__global__ void prep_enc(const float* __restrict__ emb, const int* __restrict__ seq,
                         const float* __restrict__ Wih, const float* __restrict__ bih,
                         float* __restrict__ giE)
{
  __shared__ __align__(16) float sx[64];
  const int it = blockIdx.x, t = threadIdx.x;
  if (t < 64) sx[t] = emb[(size_t)seq[it]*64 + t];
  __syncthreads();
  if (t < 192) giE[it*192 + t] = bih[t] + dotgf(Wih + (size_t)t*128, sx, 16);
}

__global__ void prep_dec(const float* __restrict__ emb2, const int* __restrict__ seq3,
                         const float* __restrict__ Wih, const float* __restrict__ bih,
                         float* __restrict__ giE)
{
  __shared__ __align__(16) float sx[64];
  const int it = blockIdx.x, t = threadIdx.x;
  const int tok = (it == 0) ? 136 : seq3[it-1];
  if (t < 64) sx[t] = emb2[(size_t)tok*64 + t];
  __syncthreads();
  if (t < 384) giE[it*384 + t] = bih[t] + dotgf(Wih + (size_t)t*192, sx, 16);
}

// ---------------- pack: dec Whh^T + ifw^T, bf16-pair [k2][r] ----------------
//  pk u32 layout: [0,24576) Whh^T (r<384, k2<64) ; [24576,33280) ifw^T (r<136, k2<64)
__global__ void pack_weights(const float* __restrict__ dWhh, const float* __restrict__ ifwW,
                             float* __restrict__ pk)
{
  const int i = blockIdx.x * 256 + threadIdx.x;
  u32* pku = (u32*)pk;
  if (i < 24576) {
    int r = i >> 6, k2 = i & 63;
    pku[k2*384 + r] = pk2(dWhh[r*128 + 2*k2], dWhh[r*128 + 2*k2 + 1]);
  } else if (i < 33280) {
    int p = i - 24576;
    int r = p >> 6, k2 = p & 63;
    pku[24576 + k2*136 + r] = pk2(ifwW[r*128 + 2*k2], ifwW[r*128 + 2*k2 + 1]);
  }
}

// ---------------- encoder: 512 sequential DNC steps, 1 block per encoder ----------------
// R8 structure (6 barriers), bf16 weights in regs, f32 activations,
// DPP rotate-reduce butterflies + readlane broadcasts + fast transcendentals.
// stout per encoder (1440 f32):
//  [0,64) h | [64,128) lr | [128,144) rw | [144,160) mem norms | [160,1184) mem | [1184,1440) link
__global__ __launch_bounds__(512) void enc_kernel(
    const float* __restrict__ Wih1, const float* __restrict__ Whh1, const float* __restrict__ bhh1,
    const float* __restrict__ iW1, const float* __restrict__ ib1,
    const float* __restrict__ Wih2, const float* __restrict__ Whh2, const float* __restrict__ bhh2,
    const float* __restrict__ iW2, const float* __restrict__ ib2,
    const float* __restrict__ giE_all, float* __restrict__ stout)
{
  __shared__ __align__(16) float s_giE[64*192];   // 64-step gi_emb chunk (49 KB)
  __shared__ __align__(16) float s_h[64];
  __shared__ __align__(16) float s_hc[64];
  __shared__ __align__(16) float s_lr[64];
  __shared__ float s_gi[192];
  __shared__ float s_ghb[2][192];                 // gh pipeline (double buffer)
  __shared__ float s_xi[264];
  __shared__ float s_mem[16][65];                 // padded: conflict-free
  __shared__ float s_link[16][16];
  __shared__ float s_prec[2][16];
  __shared__ float s_rw[16], s_ww[16], s_usage[16];
  __shared__ float s_norm[16], s_sim[16], s_fw[16];
  __shared__ float s_rk[64], s_ev[64], s_wv[64];  // hoisted activations
  __shared__ float s_sc[8]; // 0:rs 1:ws 3:ag 4:wg 5..7:rm
  __shared__ float s_wkn, s_rkn;

  const int t = threadIdx.x;
  const int e = blockIdx.x;
  const float* Wih = e ? Wih2 : Wih1;
  const float* Whh = e ? Whh2 : Whh1;
  const float* bhh = e ? bhh2 : bhh1;
  const float* iW  = e ? iW2  : iW1;
  const float* ib  = e ? ib2  : ib1;
  const float* giE = giE_all + (size_t)e * 512 * 192;

  // register weights: wA = gi rows (t<192); w2 = xi rows (t<264) OR gh rows (264<=t<456)
  u32 wA[32], w2[32];
  float b2 = 0.f;
  if (t < 192) ldrow64pk(wA, Wih + (size_t)t*128 + 64);
  if (t < 264)      { ldrow64pk(w2, iW + (size_t)t*64);        b2 = ib[t]; }
  else if (t < 456) { ldrow64pk(w2, Whh + (size_t)(t-264)*64); b2 = bhh[t-264]; }

  if (t < 192) s_ghb[0][t] = bhh[t];     // h0 = 0 -> gh(step0) = bhh
  if (t < 64) { s_h[t] = 0.f; s_lr[t] = 0.f; }
  if (t < 16) {
    s_rw[t] = DELTAF; s_ww[t] = DELTAF; s_usage[t] = 0.f; s_norm[t] = 0.f;
    s_prec[0][t] = 0.f; s_prec[1][t] = 0.f;
  }
  for (int i = t; i < 1040; i += 512) { int m = i / 65, c = i % 65; s_mem[m][c] = 0.f; }
  if (t < 256) (&s_link[0][0])[t] = 0.f;
  __syncthreads();

  int pb = 0;
  for (int it = 0; it < 512; ++it) {
    // ---- chunk refill (8x total, only global access) ----
    if ((it & 63) == 0) {
      const float4* src = (const float4*)(giE + it*192);
      float4* dst = (float4*)s_giE;
      for (int i = t; i < 3072; i += 512) dst[i] = src[i];
      __syncthreads();
    }
    // ---- P1: gi GEMV (reg weights, lr broadcast from LDS) ----
    if (t < 192) s_gi[t] = s_giE[(it & 63)*192 + t] + dotp64(wA, s_lr);
    __syncthreads();
    // ---- P2: GRU combine (gh from pipeline) ----
    if (t < 64) {
      const float* ghb = s_ghb[it & 1];
      float r = fsig(s_gi[t] + ghb[t]);
      float z = fsig(s_gi[64+t] + ghb[64+t]);
      float n = ftanh(s_gi[128+t] + r*ghb[128+t]);
      float h = (1.f - z)*n + z*s_h[t];
      s_h[t] = h;
      s_hc[t] = fminf(fmaxf(h, -CLIPF), CLIPF);
    }
    __syncthreads();
    // ---- P3: xi GEMV (t<264) || gh GEMV for NEXT step (264<=t<456) ----
    if (t < 264)      s_xi[t] = b2 + dotp64(w2, s_hc);
    else if (t < 456) s_ghb[(it + 1) & 1][t - 264] = b2 + dotp64(w2, s_h);
    __syncthreads();
    // ---- S1: write-key sim (16-lane DPP) + norms (16-lane DPP) + usage + scalars + hoists ----
    {
      int m = (t >> 4) & 15, l = t & 15;
      float p = 0.f;
#pragma unroll
      for (int i = 0; i < 4; ++i) {
        int el = l*4 + i;
        float wk = ftanh(s_xi[65+el]);
        p = fmaf(wk, s_mem[m][el], p);
      }
      p = dsum16(p);
      if (l == 0 && t < 256) s_sim[m] = p;   // raw dot; normalized later
    }
    if (t < 64) {
      s_ev[t] = fsig(s_xi[130+t]);
    } else if (t < 80) {                      // read-key norm: wave1 row0 (16 lanes x 4 elems)
      int l = t - 64;
      float q = 0.f;
#pragma unroll
      for (int i = 0; i < 4; ++i) { float v = ftanh(s_xi[l*4+i]); q = fmaf(v, v, q); }
      q = dsum16(q);
      if (t == 64) s_rkn = sqrtf(q);
    } else if (t < 96) {                      // write-key norm: wave1 row1
      int l = t - 80;
      float q = 0.f;
#pragma unroll
      for (int i = 0; i < 4; ++i) { float v = ftanh(s_xi[65 + l*4+i]); q = fmaf(v, v, q); }
      q = dsum16(q);
      if (t == 80) s_wkn = sqrtf(q);
    } else if (t >= 192 && t < 208) {
      int j = t - 192;                        // usage update (prev ww, prev rw, this fg)
      float fg = fsig(s_xi[258]);
      float u = s_usage[j];
      u = u + (1.f - u) * s_ww[j];
      u = u * (1.f - fg * s_rw[j]);
      s_usage[j] = u;
    } else if (t == 208) s_sc[0] = softplusf(s_xi[64]);
    else if (t == 209) s_sc[1] = softplusf(s_xi[129]);
    else if (t == 210) s_sc[3] = fsig(s_xi[259]);
    else if (t == 211) s_sc[4] = fsig(s_xi[260]);
    else if (t == 212) {
      float a = s_xi[261], b = s_xi[262], c = s_xi[263];
      float mx = fmaxf(a, fmaxf(b, c));
      float ea = fexp(a-mx), eb = fexp(b-mx), ec = fexp(c-mx);
      float s = frcp(ea + eb + ec);
      s_sc[5] = ea*s; s_sc[6] = eb*s; s_sc[7] = ec*s;
    } else if (t >= 384 && t < 448) {
      int l = t - 384;                        // hoisted read-key tanh
      s_rk[l] = ftanh(s_xi[l]);
    } else if (t >= 448) {
      int l = t - 448;                        // hoisted write-vector tanh
      s_wv[l] = ftanh(s_xi[194+l]);
    }
    __syncthreads();
    // ---- S23: per-row redundant write-softmax/alloc (DPP); mem write (readlane); link+fw; prec ----
    {
      int row = t & 15;
      float x = s_sim[row] * frcp((s_norm[row] + DELTAF) * (s_wkn + DELTAF)) * s_sc[1];
      float mx = dmax16(x);
      float ex = fexp(x - mx);
      float sm = dsum16(ex);
      float wcw = ex * frcp(sm);
      float um = DELTAF + (1.f - DELTAF) * s_usage[row];
      float prod = 1.f;
#pragma unroll
      for (int j = 0; j < 16; ++j) {
        float v = DELTAF + (1.f - DELTAF) * s_usage[j];
        bool before = (v < um) || ((v == um) && (j < row));  // stable argsort order
        prod *= before ? v : 1.f;
      }
      float alloc = (1.f - um) * prod;
      float wwv = s_sc[4] * (s_sc[3]*alloc + (1.f - s_sc[3])*wcw);
      float S = dsum16(wwv);
      if (t < 16) s_ww[t] = wwv;              // for next step's usage update
      // memory write: m uniform per wave per q -> readlane broadcast (SALU)
#pragma unroll
      for (int q = 0; q < 2; ++q) {
        int idx = t + q*512;
        int m = idx >> 6, wi = idx & 63;
        float wwm = rdlane(wwv, m);
        s_mem[m][wi] = s_mem[m][wi] * (1.f - wwm * s_ev[wi]) + wwm * s_wv[wi];
      }
      if (t < 256) {                          // link + fw (waves 0..3)
        int i = t >> 4, j = t & 15;           // j == row
        float wwi = __shfl(wwv, i);           // per-lane gather (keep, 1 ds op)
        float lv = (i == j) ? 0.f
                 : ((1.f - wwi - wwv) * s_link[i][j] + wwi * s_prec[pb][j]);
        s_link[i][j] = lv;
        float p = dsum16(lv * s_rw[j]);
        if (j == 0) s_fw[i] = p;
      } else if (t < 272) {                   // precedence (wave 4, lanes 0..15)
        int j = t - 256;                      // == row
        s_prec[pb^1][j] = (1.f - S) * s_prec[pb][j] + wwv;
      }
    }
    __syncthreads();
    // ---- S45: wave-0 mega-phase: read sim+norm (quad DPP) + bw + softmax (DPP) + rw + lr ----
    if (t < 64) {
      int l = t;
      int r4 = l >> 2, seg = l & 3;
      float p = 0.f, q = 0.f;
#pragma unroll
      for (int i = 0; i < 16; ++i) {
        int el = seg*16 + i;
        float mv = s_mem[r4][el];
        p = fmaf(s_rk[el], mv, p);
        q = fmaf(mv, mv, q);
      }
      p = dsum4(p); q = dsum4(q);
      int row = l & 15;
      float simv  = __shfl(p, 4*row);          // fixed permutation gather
      float normv = sqrtf(__shfl(q, 4*row));
      float b = 0.f;                           // bw_row, partial over j
#pragma unroll
      for (int jj = 0; jj < 4; ++jj) {
        int j = (l >> 4)*4 + jj;
        b = fmaf(s_link[j][row], s_rw[j], b);
      }
      b += __shfl_xor(b,16); b += __shfl_xor(b,32);
      float x = simv * frcp((normv + DELTAF) * (s_rkn + DELTAF)) * s_sc[0];
      float mx = dmax16(x);
      float ex = fexp(x - mx);
      float sm = dsum16(ex);
      float cw = ex * frcp(sm);
      float rwv = s_sc[5]*b + s_sc[6]*s_fw[row] + s_sc[7]*cw;
      if (l < 16) { s_rw[l] = rwv; s_norm[l] = normv; }   // norm carried to next step
      float a = 0.f;
#pragma unroll
      for (int m = 0; m < 16; ++m) a = fmaf(rdlane(rwv, m), s_mem[m][l], a);
      s_lr[l] = a;
    }
    pb ^= 1;
    __syncthreads();
  }

  float* so = stout + (size_t)e * 1440;
  if (t < 64) { so[t] = s_h[t]; so[64+t] = s_lr[t]; }
  if (t < 16) { so[128+t] = s_rw[t]; so[144+t] = s_norm[t]; }
  for (int i = t; i < 1024; i += 512) { int m = i >> 6, c = i & 63; so[160+i] = s_mem[m][c]; }
  if (t < 256) so[1184+t] = (&s_link[0][0])[t];
}

// ---------------- decoder: 65 steps; Wih in regs, ifw in LDS, only Whh streamed (R8 verbatim) ----------------
__global__ __launch_bounds__(512) void dec_kernel(
    const float* __restrict__ bhh, const float* __restrict__ ifwb,
    const float* __restrict__ dWih,
    const float* __restrict__ giE, const float* __restrict__ st,
    const float* __restrict__ pk, float* __restrict__ r12h)
{
  __shared__ u32 s_pIfw[8704];                 // ifw^T bf16-pair [k2][r] (34 KB)
  __shared__ __align__(16) float s_h[128];
  __shared__ __align__(16) float s_r12[128];
  __shared__ float s_gi[384], s_ghb[2][384], s_xi[136];
  __shared__ __align__(16) float s_mem[2][16][64];
  __shared__ float s_link[2][16][16];
  __shared__ float s_rw[2][16], s_norm[2][16];
  __shared__ float s_sim[2][16], s_fw[2][16], s_bw[2][16];
  __shared__ float s_rs[2], s_rkn[2];
  __shared__ float s_rm[2][3];
  __shared__ float s_bhh[384], s_ifwb[136];

  const int t = threadIdx.x;
  const u32* pWhh = (const u32*)pk;            // [k2*384 + r]
  const u32* pIfw = (const u32*)pk + 24576;    // [k2*136 + r]

  u32 w1[64];                                  // Wih-x row t (t<384), bf16
  if (t < 384) ldrow128pk(w1, dWih + (size_t)t*192 + 64);

  for (int i = t; i < 8704; i += 512) s_pIfw[i] = pIfw[i];
  if (t < 384) s_bhh[t]  = bhh[t];
  if (t < 136) s_ifwb[t] = ifwb[t];
  if (t < 64) {
    s_h[t]      = st[t];        s_h[64+t]   = st[1440+t];
    s_r12[t]    = st[64+t];     s_r12[64+t] = st[1440+64+t];
  }
  if (t < 16) {
    s_rw[0][t]   = st[128+t];   s_rw[1][t]   = st[1440+128+t];
    s_norm[0][t] = st[144+t];   s_norm[1][t] = st[1440+144+t];
  }
  for (int i = t; i < 1024; i += 512) {
    (&s_mem[0][0][0])[i] = st[160+i];
    (&s_mem[1][0][0])[i] = st[1440+160+i];
  }
  if (t < 256) {
    (&s_link[0][0][0])[t] = st[1184+t];
    (&s_link[1][0][0])[t] = st[1440+1184+t];
  }
  __syncthreads();

  // prologue: gh(step 0) = bhh + Whh . h0 (streamed)
  if (t < 384) {
    float a = 0.f;
#pragma unroll 8
    for (int k2 = 0; k2 < 64; ++k2) {
      u32 wp = pWhh[k2*384 + t];
      float2 xh = *(const float2*)&s_h[2*k2];
      a = fmaf(bl(wp), xh.x, fmaf(bh(wp), xh.y, a));
    }
    s_ghb[0][t] = s_bhh[t] + a;
  }
  __syncthreads();

  float gcur = (t < 384) ? giE[t] : 0.f;

  for (int it = 0; it < 65; ++it) {
    // ---- P1: gi (reg weights, x=[r1;r2]) ----
    if (t < 384) {
      int nx = (it + 1 < 65) ? (it + 1) : 64;
      float gn = giE[nx*384 + t];
      s_gi[t] = gcur + dotp128(w1, s_r12);
      gcur = gn;
    }
    __syncthreads();
    // ---- P2: GRU (H=128), gh from pipeline ----
    if (t < 128) {
      const float* ghb = s_ghb[it & 1];
      float r = fsig(s_gi[t] + ghb[t]);
      float z = fsig(s_gi[128+t] + ghb[128+t]);
      float n = ftanh(s_gi[256+t] + r*ghb[256+t]);
      s_h[t] = (1.f - z)*n + z*s_h[t];
    }
    __syncthreads();
    // ---- P3: gh(next) streamed (t<384) || xi from LDS (t>=384) ----
    if (t < 384) {
      float a = 0.f;
#pragma unroll 8
      for (int k2 = 0; k2 < 64; ++k2) {
        u32 wp = pWhh[k2*384 + t];
        float2 xh = *(const float2*)&s_h[2*k2];
        a = fmaf(bl(wp), xh.x, fmaf(bh(wp), xh.y, a));
      }
      s_ghb[(it + 1) & 1][t] = s_bhh[t] + a;
    } else {
      int r0 = t - 384;
      float c0 = 0.f;
#pragma unroll 8
      for (int k2 = 0; k2 < 64; ++k2) {
        u32 u = s_pIfw[k2*136 + r0];
        float2 xh = *(const float2*)&s_h[2*k2];
        c0 = fmaf(bl(u), xh.x, fmaf(bh(u), xh.y, c0));
      }
      s_xi[r0] = s_ifwb[r0] + c0;
      if (r0 < 8) {
        int r1 = 128 + r0;
        float c1 = 0.f;
#pragma unroll 8
        for (int k2 = 0; k2 < 64; ++k2) {
          u32 u = s_pIfw[k2*136 + r1];
          float2 xh = *(const float2*)&s_h[2*k2];
          c1 = fmaf(bl(u), xh.x, fmaf(bh(u), xh.y, c1));
        }
        s_xi[r1] = s_ifwb[r1] + c1;
      }
    }
    __syncthreads();
    // ---- S1: per-half sim (raw) + rk norm + fw/bw + scalars ----
    {
      int half = t >> 8, u = t & 255;
      int m = u >> 4, l = u & 15;
      float p = 0.f;
#pragma unroll
      for (int i = 0; i < 4; ++i) {
        float rk = ftanh(s_xi[half*64 + l*4 + i]);
        p = fmaf(rk, s_mem[half][m][l*4+i], p);
      }
      p += __shfl_xor(p,1); p += __shfl_xor(p,2); p += __shfl_xor(p,4); p += __shfl_xor(p,8);
      if (l == 0) s_sim[half][m] = p;   // raw
      if (u < 64) {
        float v = ftanh(s_xi[half*64 + u]);
        float q = v*v;
        q += __shfl_xor(q,1); q += __shfl_xor(q,2); q += __shfl_xor(q,4);
        q += __shfl_xor(q,8); q += __shfl_xor(q,16); q += __shfl_xor(q,32);
        if (u == 0) s_rkn[half] = sqrtf(q);
      } else if (u < 80) {
        int i = u - 64;
        float a = 0.f;
#pragma unroll
        for (int j = 0; j < 16; ++j) a = fmaf(s_link[half][i][j], s_rw[half][j], a);
        s_fw[half][i] = a;
      } else if (u < 96) {
        int i = u - 80;
        float a = 0.f;
#pragma unroll
        for (int j = 0; j < 16; ++j) a = fmaf(s_link[half][j][i], s_rw[half][j], a);
        s_bw[half][i] = a;
      } else if (u == 96) {
        s_rs[half] = softplusf(s_xi[128 + half]);
        float a = s_xi[130 + half*3], b = s_xi[131 + half*3], c = s_xi[132 + half*3];
        float mx = fmaxf(a, fmaxf(b, c));
        float ea = fexp(a-mx), eb = fexp(b-mx), ec = fexp(c-mx);
        float s = frcp(ea+eb+ec);
        s_rm[half][0] = ea*s; s_rm[half][1] = eb*s; s_rm[half][2] = ec*s;
      }
    }
    __syncthreads();
    // ---- S2: per-half softmax + rw + read vector; h store for deferred logits ----
    if (t < 128) {
      int half = t >> 6, lane = t & 63;
      float rwv = 0.f;
      if (lane < 16) {
        float x = s_sim[half][lane] * frcp((s_norm[half][lane] + DELTAF)*(s_rkn[half] + DELTAF)) * s_rs[half];
        float mx = x;
        mx = fmaxf(mx, __shfl_xor(mx,1)); mx = fmaxf(mx, __shfl_xor(mx,2));
        mx = fmaxf(mx, __shfl_xor(mx,4)); mx = fmaxf(mx, __shfl_xor(mx,8));
        float ex = fexp(x - mx);
        float sm = ex;
        sm += __shfl_xor(sm,1); sm += __shfl_xor(sm,2); sm += __shfl_xor(sm,4); sm += __shfl_xor(sm,8);
        float cw = ex * frcp(sm);
        rwv = s_rm[half][0]*s_bw[half][lane] + s_rm[half][1]*s_fw[half][lane] + s_rm[half][2]*cw;
        s_rw[half][lane] = rwv;
      }
      float a = 0.f;
#pragma unroll
      for (int m = 0; m < 16; ++m) a = fmaf(__shfl(rwv, m), s_mem[half][m][t & 63], a);
      s_r12[half*64 + (t&63)] = a;
      r12h[it*256 + half*64 + (t&63)] = a;
    } else if (t < 256) {
      r12h[it*256 + t] = s_h[t - 128];
    }
    __syncthreads();
  }
}

// ---------------- deferred logits ----------------
__global__ void logits_kernel(
    const float* __restrict__ r2oW, const float* __restrict__ r2ob,
    const float* __restrict__ outW, const float* __restrict__ outb,
    const float* __restrict__ r12h, float* __restrict__ out)
{
  __shared__ __align__(16) float s_in[128];
  __shared__ __align__(16) float s_oh[128];
  const int it = blockIdx.x, t = threadIdx.x;
  if (t < 128) s_in[t] = r12h[it*256 + t];
  __syncthreads();
  if (t < 128) {
    float o = r2ob[t] + dotgf(r2oW + (size_t)t*128, s_in, 32);
    s_oh[t] = o + r12h[it*256 + 128 + t];
  }
  __syncthreads();
  if (t < 138) {
    out[it*138 + t] = outb[t] + dotgf(outW + (size_t)t*128, s_oh, 32);
  }
}

extern "C" void kernel_launch(void* const* d_in, const int* in_sizes, int n_in,
                              void* d_out, int out_size, void* d_ws, size_t ws_size,
                              hipStream_t stream) {
  (void)in_sizes; (void)n_in; (void)out_size; (void)ws_size;
  const float* emb0   = (const float*)d_in[0];
  const float* emb1   = (const float*)d_in[1];
  const float* emb2   = (const float*)d_in[2];
  const float* e1_Wih = (const float*)d_in[3];
  const float* e1_Whh = (const float*)d_in[4];
  const float* e1_bih = (const float*)d_in[5];
  const float* e1_bhh = (const float*)d_in[6];
  const float* e1_iW  = (const float*)d_in[7];
  const float* e1_ib  = (const float*)d_in[8];
  const float* e2_Wih = (const float*)d_in[9];
  const float* e2_Whh = (const float*)d_in[10];
  const float* e2_bih = (const float*)d_in[11];
  const float* e2_bhh = (const float*)d_in[12];
  const float* e2_iW  = (const float*)d_in[13];
  const float* e2_ib  = (const float*)d_in[14];
  const float* dWih   = (const float*)d_in[15];
  const float* dWhh   = (const float*)d_in[16];
  const float* dbih   = (const float*)d_in[17];
  const float* dbhh   = (const float*)d_in[18];
  const float* ifwW   = (const float*)d_in[19];
  const float* ifwb   = (const float*)d_in[20];
  const float* r2oW   = (const float*)d_in[21];
  const float* r2ob   = (const float*)d_in[22];
  const float* outW   = (const float*)d_in[23];
  const float* outb   = (const float*)d_in[24];
  const int* seq1     = (const int*)d_in[25];
  const int* seq2     = (const int*)d_in[26];
  const int* seq3     = (const int*)d_in[27];

  float* ws   = (float*)d_ws;
  float* giE1 = ws;                    // 512*192 = 98304
  float* giE2 = giE1 + 98304;          // 98304 (contiguous with giE1)
  float* giEd = giE2 + 98304;          // 65*384 = 24960
  float* st   = giEd + 24960;          // 2*1440 = 2880
  float* r12h = st + 2880;             // 65*256 = 16640
  float* pkw  = r12h + 16640;          // 33280 u32 packed (dec Whh + ifw)

  prep_enc<<<512, 192, 0, stream>>>(emb0, seq1, e1_Wih, e1_bih, giE1);
  prep_enc<<<512, 192, 0, stream>>>(emb1, seq2, e2_Wih, e2_bih, giE2);
  prep_dec<<<65, 384, 0, stream>>>(emb2, seq3, dWih, dbih, giEd);
  pack_weights<<<(33280 + 255) / 256, 256, 0, stream>>>(dWhh, ifwW, pkw);
  enc_kernel<<<2, 512, 0, stream>>>(e1_Wih, e1_Whh, e1_bhh, e1_iW, e1_ib,
                                    e2_Wih, e2_Whh, e2_bhh, e2_iW, e2_ib, giE1, st);
  dec_kernel<<<1, 512, 0, stream>>>(dbhh, ifwb, dWih, giEd, st, pkw, r12h);
  logits_kernel<<<65, 256, 0, stream>>>(r2oW, r2ob, outW, outb, r12h, (float*)d_out);
}